// Round 3
// baseline (339.482 us; speedup 1.0000x reference)
//
#include <hip/hip_runtime.h>
#include <hip/hip_bf16.h>

typedef float fx4 __attribute__((ext_vector_type(4)));
typedef short s16x8 __attribute__((ext_vector_type(8)));

#define NSEQ 2048
#define DM   1024
#define NH   16
#define DH   64
#define MROWS 4096   // B * NSEQ

__device__ __forceinline__ unsigned short f2bf(float f) {
    union { float f; unsigned u; } c; c.f = f;
    unsigned u = c.u;
    unsigned r = u + 0x7FFFu + ((u >> 16) & 1u);   // round-to-nearest-even
    return (unsigned short)(r >> 16);
}

__device__ __forceinline__ fx4 zero4() {
    fx4 z; z[0] = 0.f; z[1] = 0.f; z[2] = 0.f; z[3] = 0.f; return z;
}

// ---------------- fp32 -> bf16 conversion (vectorized) ----------------
__global__ void cvt_kernel(const float* __restrict__ in,
                           unsigned short* __restrict__ out, int n4) {
    int i = blockIdx.x * blockDim.x + threadIdx.x;
    if (i >= n4) return;
    float4 v = reinterpret_cast<const float4*>(in)[i];
    ushort4 o;
    o.x = f2bf(v.x); o.y = f2bf(v.y); o.z = f2bf(v.z); o.w = f2bf(v.w);
    reinterpret_cast<ushort4*>(out)[i] = o;
}

// ---------------- mask dtype detection ----------------
// Reads the mask as u32 words over exactly 8 MB (= full buffer if bool bytes,
// first quarter if int32). int32 0/1 data can never produce a word > 1;
// packed bool bytes will (e.g. 0x00010100). Sets *flag = 1 if bytes.
__global__ void mask_detect(const unsigned int* __restrict__ m, int* __restrict__ flag) {
    unsigned mx = 0;
    int stride = gridDim.x * blockDim.x;
    for (int i = blockIdx.x * blockDim.x + threadIdx.x; i < (2 * NSEQ * NSEQ) / 4; i += stride) {
        unsigned v = m[i];
        mx = v > mx ? v : mx;
    }
    if (__any(mx > 1u)) {
        if ((threadIdx.x & 63) == 0) atomicOr(flag, 1);
    }
}

// ---------------- bf16 GEMM: C[m][c] = sum_k A[m][k] * W[c][k] ----------------
// 128x128 tile, 256 threads = 4 waves (2x2 of 64x64), BK=32, mfma 16x16x32.
// MODE 0: obf[((b*16+h)*2048+n)*64+dh]   (Q/K head-major), *scale
// MODE 1: obf[((b*16+h)*64+dh)*2048+n]   (V transposed)
// MODE 2: fp32 ofp[m*1024+c] + bias[c]
// AFP32: A operand is fp32 (converted to bf16 during LDS staging)
template<int MODE, bool AFP32>
__global__ __launch_bounds__(256) void gemm_bt(
        const unsigned short* __restrict__ Abf,
        const float* __restrict__ Afp,
        const unsigned short* __restrict__ W,
        float scale,
        unsigned short* __restrict__ obf,
        float* __restrict__ ofp,
        const float* __restrict__ bias) {
    __shared__ unsigned short As[128][40];   // 80B row stride (16B-mult)
    __shared__ unsigned short Bs[128][40];

    const int tid  = threadIdx.x;
    const int lane = tid & 63;
    const int w    = tid >> 6;
    const int lr   = lane & 15;
    const int lg   = lane >> 4;
    const int wr   = (w >> 1) * 64;
    const int wc   = (w & 1) * 64;
    const int rowbase = blockIdx.y * 128;
    const int colbase = blockIdx.x * 128;

    fx4 acc[4][4];
#pragma unroll
    for (int i = 0; i < 4; i++)
#pragma unroll
        for (int j = 0; j < 4; j++) acc[i][j] = zero4();

    for (int k0 = 0; k0 < DM; k0 += 32) {
        __syncthreads();
#pragma unroll
        for (int i = 0; i < 2; i++) {
            int u  = tid + i * 256;          // 0..511
            int r  = u >> 2, cu = u & 3;     // row, 8-elem unit
            s16x8 av;
            if constexpr (AFP32) {
                const float* src = Afp + (size_t)(rowbase + r) * DM + k0 + cu * 8;
                float4 f0 = *reinterpret_cast<const float4*>(src);
                float4 f1 = *reinterpret_cast<const float4*>(src + 4);
                av[0] = (short)f2bf(f0.x); av[1] = (short)f2bf(f0.y);
                av[2] = (short)f2bf(f0.z); av[3] = (short)f2bf(f0.w);
                av[4] = (short)f2bf(f1.x); av[5] = (short)f2bf(f1.y);
                av[6] = (short)f2bf(f1.z); av[7] = (short)f2bf(f1.w);
            } else {
                av = *reinterpret_cast<const s16x8*>(Abf + (size_t)(rowbase + r) * DM + k0 + cu * 8);
            }
            *reinterpret_cast<s16x8*>(&As[r][cu * 8]) = av;
            s16x8 bv = *reinterpret_cast<const s16x8*>(W + (size_t)(colbase + r) * DM + k0 + cu * 8);
            *reinterpret_cast<s16x8*>(&Bs[r][cu * 8]) = bv;
        }
        __syncthreads();

        s16x8 af[4], bf[4];
#pragma unroll
        for (int mi = 0; mi < 4; mi++)
            af[mi] = *reinterpret_cast<const s16x8*>(&As[wr + mi * 16 + lr][8 * lg]);
#pragma unroll
        for (int ni = 0; ni < 4; ni++)
            bf[ni] = *reinterpret_cast<const s16x8*>(&Bs[wc + ni * 16 + lr][8 * lg]);
#pragma unroll
        for (int mi = 0; mi < 4; mi++)
#pragma unroll
            for (int ni = 0; ni < 4; ni++)
                acc[mi][ni] = __builtin_amdgcn_mfma_f32_16x16x32_bf16(af[mi], bf[ni], acc[mi][ni], 0, 0, 0);
    }

    // epilogue: D lane map: row=(lane>>4)*4+v, col=lane&15 within each 16x16
#pragma unroll
    for (int mi = 0; mi < 4; mi++) {
#pragma unroll
        for (int ni = 0; ni < 4; ni++) {
#pragma unroll
            for (int v = 0; v < 4; v++) {
                int m = rowbase + wr + mi * 16 + lg * 4 + v;
                int c = colbase + wc + ni * 16 + lr;
                float val = acc[mi][ni][v] * scale;
                if constexpr (MODE == 2) {
                    ofp[(size_t)m * DM + c] = val + bias[c];
                } else {
                    int b = m >> 11, nseq = m & 2047;
                    int h = c >> 6,  dh   = c & 63;
                    if constexpr (MODE == 0)
                        obf[((size_t)(b * NH + h) * NSEQ + nseq) * DH + dh] = f2bf(val);
                    else
                        obf[((size_t)(b * NH + h) * DH + dh) * NSEQ + nseq] = f2bf(val);
                }
            }
        }
    }
}

// ---------------- flash attention ----------------
// grid: x = N/64 q-tiles, y = B*H. 256 threads = 4 waves, wave w owns q rows w*16..+15.
__global__ __launch_bounds__(256) void attn_kernel(
        const unsigned short* __restrict__ Qh,   // [B,H,N,64] bf16 (pre-scaled)
        const unsigned short* __restrict__ Kh,   // [B,H,N,64] bf16
        const unsigned short* __restrict__ VhT,  // [B,H,64,N] bf16
        const void* __restrict__ mask,           // [B,N,N] int32 OR bool bytes
        const int* __restrict__ mflag,           // 1 = bytes, 0 = int32
        float* __restrict__ Obuf) {              // [B,N,1024] fp32
    __shared__ unsigned short Ks[64 * 64];       // XOR-swizzled rows
    __shared__ unsigned short Vs[64 * 64];       // XOR-swizzled rows (V^T: row=d, col=key)
    __shared__ unsigned short Ps[4][16][72];     // per-wave P tile: 16 q x 64 keys, +8 pad

    const int tid  = threadIdx.x;
    const int lane = tid & 63;
    const int w    = tid >> 6;
    const int lr   = lane & 15;
    const int lg   = lane >> 4;
    const int qbase = blockIdx.x * 64;
    const int bh    = blockIdx.y;
    const int b     = bh >> 4;
    const int h     = bh & 15;
    const int flg   = __builtin_amdgcn_readfirstlane(mflag[0]);

    // Q fragments live in registers for the whole kernel
    s16x8 qf[2];
    const size_t qrow0 = (size_t)bh * NSEQ + qbase + w * 16 + lr;
#pragma unroll
    for (int kk = 0; kk < 2; kk++)
        qf[kk] = *reinterpret_cast<const s16x8*>(Qh + qrow0 * DH + kk * 32 + 8 * lg);

    float mrow[4], lrow[4];
    fx4 acc[4];
#pragma unroll
    for (int v = 0; v < 4; v++) { mrow[v] = -3.0e38f; lrow[v] = 0.f; }
#pragma unroll
    for (int t = 0; t < 4; t++) acc[t] = zero4();

    const int qglob = qbase + w * 16 + lg * 4;   // first of this lane's 4 q rows

    for (int kv0 = 0; kv0 < NSEQ; kv0 += 64) {
        __syncthreads();
        // stage K tile [64 keys][64 d] and V^T tile [64 d][64 keys], XOR-swizzled
#pragma unroll
        for (int i = 0; i < 2; i++) {
            int u  = tid + i * 256;              // 0..511
            int r  = u >> 3, cu = u & 7;         // row, 8-elem unit
            int cs = cu ^ (r & 7);
            s16x8 kv = *reinterpret_cast<const s16x8*>(Kh + ((size_t)bh * NSEQ + kv0 + r) * DH + cu * 8);
            *reinterpret_cast<s16x8*>(&Ks[r * 64 + cs * 8]) = kv;
            s16x8 vv = *reinterpret_cast<const s16x8*>(VhT + ((size_t)bh * DH + r) * NSEQ + kv0 + cu * 8);
            *reinterpret_cast<s16x8*>(&Vs[r * 64 + cs * 8]) = vv;
        }
        __syncthreads();

        // mask for this lane's 4 q rows x 4 key sub-tiles (uniform dtype branch)
        int mk[4][4];
        if (flg) {
            const unsigned char* mb = (const unsigned char*)mask;
#pragma unroll
            for (int t = 0; t < 4; t++)
#pragma unroll
                for (int v = 0; v < 4; v++)
                    mk[t][v] = mb[((size_t)b * NSEQ + qglob + v) * NSEQ + kv0 + t * 16 + lr];
        } else {
            const int* mi = (const int*)mask;
#pragma unroll
            for (int t = 0; t < 4; t++)
#pragma unroll
                for (int v = 0; v < 4; v++)
                    mk[t][v] = mi[((size_t)b * NSEQ + qglob + v) * NSEQ + kv0 + t * 16 + lr];
        }

        // S = Q K^T  (per wave: 16 q-rows x 64 keys)
        fx4 s[4];
#pragma unroll
        for (int t = 0; t < 4; t++) {
            s[t] = zero4();
#pragma unroll
            for (int kk = 0; kk < 2; kk++) {
                int r  = t * 16 + lr;
                int cu = kk * 4 + lg;
                int cs = cu ^ (r & 7);
                s16x8 kf = *reinterpret_cast<const s16x8*>(&Ks[r * 64 + cs * 8]);
                s[t] = __builtin_amdgcn_mfma_f32_16x16x32_bf16(qf[kk], kf, s[t], 0, 0, 0);
            }
        }

        // mask + online softmax (lane owns q rows qglob..+3; reduce over 16 lanes of same lg)
        float tmax[4];
#pragma unroll
        for (int v = 0; v < 4; v++) tmax[v] = -3.0e38f;
#pragma unroll
        for (int t = 0; t < 4; t++)
#pragma unroll
            for (int v = 0; v < 4; v++) {
                float sv = mk[t][v] ? -3.0e38f : s[t][v];
                s[t][v] = sv;
                tmax[v] = fmaxf(tmax[v], sv);
            }
#pragma unroll
        for (int off = 1; off < 16; off <<= 1)
#pragma unroll
            for (int v = 0; v < 4; v++)
                tmax[v] = fmaxf(tmax[v], __shfl_xor(tmax[v], off));

        float sc[4], psum[4];
#pragma unroll
        for (int v = 0; v < 4; v++) {
            float mn = fmaxf(mrow[v], tmax[v]);
            sc[v]    = __expf(mrow[v] - mn);
            mrow[v]  = mn;
            psum[v]  = 0.f;
        }
#pragma unroll
        for (int t = 0; t < 4; t++)
#pragma unroll
            for (int v = 0; v < 4; v++) {
                float p = __expf(s[t][v] - mrow[v]);
                s[t][v] = p;
                psum[v] += p;
            }
#pragma unroll
        for (int off = 1; off < 16; off <<= 1)
#pragma unroll
            for (int v = 0; v < 4; v++)
                psum[v] += __shfl_xor(psum[v], off);
#pragma unroll
        for (int v = 0; v < 4; v++) lrow[v] = lrow[v] * sc[v] + psum[v];
#pragma unroll
        for (int t = 0; t < 4; t++)
#pragma unroll
            for (int v = 0; v < 4; v++) acc[t][v] *= sc[v];

        // P -> LDS (A-fragment layout for PV); wave-private, no barrier needed
#pragma unroll
        for (int t = 0; t < 4; t++)
#pragma unroll
            for (int v = 0; v < 4; v++)
                Ps[w][lg * 4 + v][t * 16 + lr] = f2bf(s[t][v]);

        // O += P V : D[q][d], A=P (row=q, k=key), B=V (k=key, col=d) read from V^T rows
#pragma unroll
        for (int kk = 0; kk < 2; kk++) {
            s16x8 pf = *reinterpret_cast<const s16x8*>(&Ps[w][lr][kk * 32 + 8 * lg]);
#pragma unroll
            for (int t = 0; t < 4; t++) {
                int r  = t * 16 + lr;
                int cu = kk * 4 + lg;
                int cs = cu ^ (r & 7);
                s16x8 vf = *reinterpret_cast<const s16x8*>(&Vs[r * 64 + cs * 8]);
                acc[t] = __builtin_amdgcn_mfma_f32_16x16x32_bf16(pf, vf, acc[t], 0, 0, 0);
            }
        }
    }

    // epilogue: Obuf[b][n][h*64+d] fp32
#pragma unroll
    for (int t = 0; t < 4; t++)
#pragma unroll
        for (int v = 0; v < 4; v++) {
            int q = qglob + v;
            int d = t * 16 + lr;
            Obuf[((size_t)b * NSEQ + q) * DM + h * DH + d] = acc[t][v] / lrow[v];
        }
}

// ---------------- launch ----------------
extern "C" void kernel_launch(void* const* d_in, const int* in_sizes, int n_in,
                              void* d_out, int out_size, void* d_ws, size_t ws_size,
                              hipStream_t stream) {
    const float* q    = (const float*)d_in[0];
    const void*  mask = (const void*)d_in[1];
    const float* Wq   = (const float*)d_in[2];
    const float* Wk   = (const float*)d_in[3];
    const float* Wv   = (const float*)d_in[4];
    const float* Wo   = (const float*)d_in[5];
    const float* bo   = (const float*)d_in[6];
    float* out = (float*)d_out;

    char* ws = (char*)d_ws;
    const size_t MB = 1024 * 1024;
    unsigned short* qbf  = (unsigned short*)(ws + 0);        // 8 MB  [4096][1024]
    unsigned short* Wqb  = (unsigned short*)(ws + 8  * MB);  // 2 MB
    unsigned short* Wkb  = (unsigned short*)(ws + 10 * MB);  // 2 MB
    unsigned short* Wvb  = (unsigned short*)(ws + 12 * MB);  // 2 MB
    unsigned short* Wob  = (unsigned short*)(ws + 14 * MB);  // 2 MB
    unsigned short* Qh   = (unsigned short*)(ws + 16 * MB);  // 8 MB  [B,H,N,64]
    unsigned short* Kh   = (unsigned short*)(ws + 24 * MB);  // 8 MB  [B,H,N,64]
    unsigned short* VhT  = (unsigned short*)(ws + 32 * MB);  // 8 MB  [B,H,64,N]
    float*          Obuf = (float*)(ws + 40 * MB);           // 16 MB [B,N,1024] fp32
    int*            flag = (int*)(ws + 56 * MB);             // 4 B

    const float SCALE = 0.125f;   // DIM_HEAD^-0.5 = 1/8

    hipMemsetAsync(flag, 0, 4, stream);
    mask_detect<<<1024, 256, 0, stream>>>((const unsigned int*)mask, flag);

    // fp32 -> bf16
    cvt_kernel<<<4096, 256, 0, stream>>>(q,  qbf, (2 * NSEQ * DM) / 4);
    cvt_kernel<<<1024, 256, 0, stream>>>(Wq, Wqb, (DM * DM) / 4);
    cvt_kernel<<<1024, 256, 0, stream>>>(Wk, Wkb, (DM * DM) / 4);
    cvt_kernel<<<1024, 256, 0, stream>>>(Wv, Wvb, (DM * DM) / 4);
    cvt_kernel<<<1024, 256, 0, stream>>>(Wo, Wob, (DM * DM) / 4);

    dim3 ggrid(DM / 128, MROWS / 128);   // (8, 32)
    gemm_bt<0, false><<<ggrid, 256, 0, stream>>>(qbf, nullptr, Wqb, SCALE, Qh,  nullptr, nullptr);
    gemm_bt<0, false><<<ggrid, 256, 0, stream>>>(qbf, nullptr, Wkb, 1.0f,  Kh,  nullptr, nullptr);
    gemm_bt<1, false><<<ggrid, 256, 0, stream>>>(qbf, nullptr, Wvb, 1.0f,  VhT, nullptr, nullptr);

    attn_kernel<<<dim3(NSEQ / 64, 32), 256, 0, stream>>>(Qh, Kh, VhT, mask, flag, Obuf);

    gemm_bt<2, true><<<ggrid, 256, 0, stream>>>(nullptr, Obuf, Wob, 1.0f, nullptr, out, bo);
}

// Round 5
// 323.407 us; speedup vs baseline: 1.0497x; 1.0497x over previous
//
#include <hip/hip_runtime.h>
#include <hip/hip_bf16.h>

typedef float fx4 __attribute__((ext_vector_type(4)));
typedef short s16x8 __attribute__((ext_vector_type(8)));

#define NSEQ 2048
#define DM   1024
#define NH   16
#define DH   64
#define MROWS 4096               // B * NSEQ
#define NWORDS (2 * NSEQ * (NSEQ / 64))   // 131072 packed-mask words

// QK scale with log2(e) folded in: softmax runs in exp2 domain.
#define QK_SCALE (0.125f * 1.44269504088896f)

__device__ __forceinline__ unsigned short f2bf(float f) {
    union { float f; unsigned u; } c; c.f = f;
    unsigned u = c.u;
    unsigned r = u + 0x7FFFu + ((u >> 16) & 1u);   // round-to-nearest-even
    return (unsigned short)(r >> 16);
}

__device__ __forceinline__ float exp2_fast(float x) {
#if __has_builtin(__builtin_amdgcn_exp2f)
    return __builtin_amdgcn_exp2f(x);
#else
    return exp2f(x);
#endif
}

__device__ __forceinline__ fx4 zero4() {
    fx4 z; z[0] = 0.f; z[1] = 0.f; z[2] = 0.f; z[3] = 0.f; return z;
}

// ---------------- fp32 -> bf16 conversion ----------------
__global__ void cvt_kernel(const float* __restrict__ in,
                           unsigned short* __restrict__ out, int n4) {
    int i = blockIdx.x * blockDim.x + threadIdx.x;
    if (i >= n4) return;
    float4 v = reinterpret_cast<const float4*>(in)[i];
    ushort4 o;
    o.x = f2bf(v.x); o.y = f2bf(v.y); o.z = f2bf(v.z); o.w = f2bf(v.w);
    reinterpret_cast<ushort4*>(out)[i] = o;
}

// 4 weight matrices in one launch (blockIdx.y selects).
// Each matrix: DM*DM/4 = 262144 float4s -> grid.x MUST be 1024 (262144/256).
__global__ void cvt4_kernel(const float* __restrict__ w0, const float* __restrict__ w1,
                            const float* __restrict__ w2, const float* __restrict__ w3,
                            unsigned short* __restrict__ o0, unsigned short* __restrict__ o1,
                            unsigned short* __restrict__ o2, unsigned short* __restrict__ o3) {
    const float* in; unsigned short* out;
    switch (blockIdx.y) {
        case 0:  in = w0; out = o0; break;
        case 1:  in = w1; out = o1; break;
        case 2:  in = w2; out = o2; break;
        default: in = w3; out = o3; break;
    }
    int i = blockIdx.x * blockDim.x + threadIdx.x;
    float4 v = reinterpret_cast<const float4*>(in)[i];
    ushort4 o;
    o.x = f2bf(v.x); o.y = f2bf(v.y); o.z = f2bf(v.z); o.w = f2bf(v.w);
    reinterpret_cast<ushort4*>(out)[i] = o;
}

// ---------------- mask dtype detection ----------------
// int32 0/1 data can never make a u32 word > 1; packed bool bytes will.
__global__ void mask_detect(const unsigned int* __restrict__ m, int* __restrict__ flag) {
    unsigned mx = 0;
    int stride = gridDim.x * blockDim.x;
    for (int i = blockIdx.x * blockDim.x + threadIdx.x; i < (2 * NSEQ * NSEQ) / 4; i += stride) {
        unsigned v = m[i];
        mx = v > mx ? v : mx;
    }
    if (__any(mx > 1u)) {
        if ((threadIdx.x & 63) == 0) atomicOr(flag, 1);
    }
}

// ---------------- mask bit-pack ----------------
// packed[w] covers keys kw*64..+63 of global row bq (w = bq*32 + kw).
// Bit position p holds key (p&3)*16 + (p>>2), so attn lane lr extracts its
// 4 bits for t=0..3 with a single >> (lr*4).
__global__ void mask_pack(const void* __restrict__ mask, const int* __restrict__ mflag,
                          unsigned long long* __restrict__ packed) {
    const int flg  = mflag[0];
    const int lane = threadIdx.x & 63;
    const int wpb  = blockDim.x >> 6;
    const int perm = (lane & 3) * 16 + (lane >> 2);
    size_t w = (size_t)blockIdx.x * wpb + (threadIdx.x >> 6);
    const size_t stride = (size_t)gridDim.x * wpb;
    for (; w < NWORDS; w += stride) {
        size_t elem = (w >> 5) * (size_t)NSEQ + (size_t)(w & 31) * 64 + perm;
        int mv = flg ? (int)((const unsigned char*)mask)[elem]
                     : ((const int*)mask)[elem];
        unsigned long long bits = __ballot(mv != 0);
        if (lane == 0) packed[w] = bits;
    }
}

// ---------------- fused QKV GEMM ----------------
// grid (24, 32): blockIdx.x>>3 selects segment (0=Q,1=K,2=V).
// C[m][c] = sum_k A[m][k] * W[c][k]; 128x128 tile, 4 waves, BK=32.
__global__ __launch_bounds__(256) void gemm_qkv(
        const unsigned short* __restrict__ A,
        const unsigned short* __restrict__ Wq,
        const unsigned short* __restrict__ Wk,
        const unsigned short* __restrict__ Wv,
        unsigned short* __restrict__ Qh,     // [B,H,N,64], pre-scaled by QK_SCALE
        unsigned short* __restrict__ Kh,     // [B,H,N,64]
        unsigned short* __restrict__ VhT) {  // [B,H,64,N]
    __shared__ unsigned short As[128][40];
    __shared__ unsigned short Bs[128][40];

    const int tid  = threadIdx.x;
    const int lane = tid & 63;
    const int w    = tid >> 6;
    const int lr   = lane & 15;
    const int lg   = lane >> 4;
    const int wr   = (w >> 1) * 64;
    const int wc   = (w & 1) * 64;
    const int rowbase = blockIdx.y * 128;
    const int seg     = blockIdx.x >> 3;              // 0,1,2
    const int cb      = (blockIdx.x & 7) * 128;       // col base within segment
    const unsigned short* W = seg == 0 ? Wq : (seg == 1 ? Wk : Wv);
    const float scale = seg == 0 ? QK_SCALE : 1.0f;

    fx4 acc[4][4];
#pragma unroll
    for (int i = 0; i < 4; i++)
#pragma unroll
        for (int j = 0; j < 4; j++) acc[i][j] = zero4();

    for (int k0 = 0; k0 < DM; k0 += 32) {
        __syncthreads();
#pragma unroll
        for (int i = 0; i < 2; i++) {
            int u  = tid + i * 256;
            int r  = u >> 2, cu = u & 3;
            s16x8 av = *reinterpret_cast<const s16x8*>(A + (size_t)(rowbase + r) * DM + k0 + cu * 8);
            *reinterpret_cast<s16x8*>(&As[r][cu * 8]) = av;
            s16x8 bv = *reinterpret_cast<const s16x8*>(W + (size_t)(cb + r) * DM + k0 + cu * 8);
            *reinterpret_cast<s16x8*>(&Bs[r][cu * 8]) = bv;
        }
        __syncthreads();

        s16x8 af[4], bf[4];
#pragma unroll
        for (int mi = 0; mi < 4; mi++)
            af[mi] = *reinterpret_cast<const s16x8*>(&As[wr + mi * 16 + lr][8 * lg]);
#pragma unroll
        for (int ni = 0; ni < 4; ni++)
            bf[ni] = *reinterpret_cast<const s16x8*>(&Bs[wc + ni * 16 + lr][8 * lg]);
#pragma unroll
        for (int mi = 0; mi < 4; mi++)
#pragma unroll
            for (int ni = 0; ni < 4; ni++)
                acc[mi][ni] = __builtin_amdgcn_mfma_f32_16x16x32_bf16(af[mi], bf[ni], acc[mi][ni], 0, 0, 0);
    }

#pragma unroll
    for (int mi = 0; mi < 4; mi++) {
#pragma unroll
        for (int ni = 0; ni < 4; ni++) {
#pragma unroll
            for (int v = 0; v < 4; v++) {
                int m    = rowbase + wr + mi * 16 + lg * 4 + v;
                int cseg = cb + wc + ni * 16 + lr;
                float val = acc[mi][ni][v] * scale;
                int b = m >> 11, nseq = m & 2047;
                int h = cseg >> 6, dh = cseg & 63;
                if (seg < 2) {
                    unsigned short* dst = seg == 0 ? Qh : Kh;
                    dst[((size_t)(b * NH + h) * NSEQ + nseq) * DH + dh] = f2bf(val);
                } else {
                    VhT[((size_t)(b * NH + h) * DH + dh) * NSEQ + nseq] = f2bf(val);
                }
            }
        }
    }
}

// ---------------- output GEMM (fp32 A, +bias, fp32 out) ----------------
__global__ __launch_bounds__(256) void gemm_out(
        const float* __restrict__ Afp,
        const unsigned short* __restrict__ W,
        float* __restrict__ out,
        const float* __restrict__ bias) {
    __shared__ unsigned short As[128][40];
    __shared__ unsigned short Bs[128][40];

    const int tid  = threadIdx.x;
    const int lane = tid & 63;
    const int w    = tid >> 6;
    const int lr   = lane & 15;
    const int lg   = lane >> 4;
    const int wr   = (w >> 1) * 64;
    const int wc   = (w & 1) * 64;
    const int rowbase = blockIdx.y * 128;
    const int colbase = blockIdx.x * 128;

    fx4 acc[4][4];
#pragma unroll
    for (int i = 0; i < 4; i++)
#pragma unroll
        for (int j = 0; j < 4; j++) acc[i][j] = zero4();

    for (int k0 = 0; k0 < DM; k0 += 32) {
        __syncthreads();
#pragma unroll
        for (int i = 0; i < 2; i++) {
            int u  = tid + i * 256;
            int r  = u >> 2, cu = u & 3;
            const float* src = Afp + (size_t)(rowbase + r) * DM + k0 + cu * 8;
            float4 f0 = *reinterpret_cast<const float4*>(src);
            float4 f1 = *reinterpret_cast<const float4*>(src + 4);
            s16x8 av;
            av[0] = (short)f2bf(f0.x); av[1] = (short)f2bf(f0.y);
            av[2] = (short)f2bf(f0.z); av[3] = (short)f2bf(f0.w);
            av[4] = (short)f2bf(f1.x); av[5] = (short)f2bf(f1.y);
            av[6] = (short)f2bf(f1.z); av[7] = (short)f2bf(f1.w);
            *reinterpret_cast<s16x8*>(&As[r][cu * 8]) = av;
            s16x8 bv = *reinterpret_cast<const s16x8*>(W + (size_t)(colbase + r) * DM + k0 + cu * 8);
            *reinterpret_cast<s16x8*>(&Bs[r][cu * 8]) = bv;
        }
        __syncthreads();

        s16x8 af[4], bf[4];
#pragma unroll
        for (int mi = 0; mi < 4; mi++)
            af[mi] = *reinterpret_cast<const s16x8*>(&As[wr + mi * 16 + lr][8 * lg]);
#pragma unroll
        for (int ni = 0; ni < 4; ni++)
            bf[ni] = *reinterpret_cast<const s16x8*>(&Bs[wc + ni * 16 + lr][8 * lg]);
#pragma unroll
        for (int mi = 0; mi < 4; mi++)
#pragma unroll
            for (int ni = 0; ni < 4; ni++)
                acc[mi][ni] = __builtin_amdgcn_mfma_f32_16x16x32_bf16(af[mi], bf[ni], acc[mi][ni], 0, 0, 0);
    }

#pragma unroll
    for (int mi = 0; mi < 4; mi++)
#pragma unroll
        for (int ni = 0; ni < 4; ni++)
#pragma unroll
            for (int v = 0; v < 4; v++) {
                int m = rowbase + wr + mi * 16 + lg * 4 + v;
                int c = colbase + wc + ni * 16 + lr;
                out[(size_t)m * DM + c] = acc[mi][ni][v] + bias[c];
            }
}

// ---------------- flash attention ----------------
// grid: x = N/64 q-tiles, y = B*H. 4 waves; wave w owns q rows w*16..+15.
__global__ __launch_bounds__(256) void attn_kernel(
        const unsigned short* __restrict__ Qh,   // [B,H,N,64] bf16 (scaled by QK_SCALE)
        const unsigned short* __restrict__ Kh,   // [B,H,N,64] bf16
        const unsigned short* __restrict__ VhT,  // [B,H,64,N] bf16
        const unsigned long long* __restrict__ Mp, // packed mask [B*N][32]
        float* __restrict__ Obuf) {              // [B,N,1024] fp32
    __shared__ unsigned short Ks[64 * 64];       // XOR-swizzled rows
    __shared__ unsigned short Vs[64 * 64];       // XOR-swizzled rows (V^T: row=d, col=key)
    __shared__ unsigned short Ps[4][16][72];     // per-wave P tile: 16 q x 64 keys

    const int tid  = threadIdx.x;
    const int lane = tid & 63;
    const int w    = tid >> 6;
    const int lr   = lane & 15;
    const int lg   = lane >> 4;
    const int qbase = blockIdx.x * 64;
    const int bh    = blockIdx.y;
    const int b     = bh >> 4;
    const int h     = bh & 15;

    s16x8 qf[2];
    const size_t qrow0 = (size_t)bh * NSEQ + qbase + w * 16 + lr;
#pragma unroll
    for (int kk = 0; kk < 2; kk++)
        qf[kk] = *reinterpret_cast<const s16x8*>(Qh + qrow0 * DH + kk * 32 + 8 * lg);

    float mrow[4], lrow[4];
    fx4 acc[4];
#pragma unroll
    for (int v = 0; v < 4; v++) { mrow[v] = -3.0e38f; lrow[v] = 0.f; }
#pragma unroll
    for (int t = 0; t < 4; t++) acc[t] = zero4();

    const int qglob = qbase + w * 16 + lg * 4;   // first of this lane's 4 q rows
    const size_t mrow0 = ((size_t)b * NSEQ + qglob) * (NSEQ / 64);

    for (int kv0 = 0; kv0 < NSEQ; kv0 += 64) {
        __syncthreads();
#pragma unroll
        for (int i = 0; i < 2; i++) {
            int u  = tid + i * 256;
            int r  = u >> 3, cu = u & 7;
            int cs = cu ^ (r & 7);
            s16x8 kv = *reinterpret_cast<const s16x8*>(Kh + ((size_t)bh * NSEQ + kv0 + r) * DH + cu * 8);
            *reinterpret_cast<s16x8*>(&Ks[r * 64 + cs * 8]) = kv;
            s16x8 vv = *reinterpret_cast<const s16x8*>(VhT + ((size_t)bh * DH + r) * NSEQ + kv0 + cu * 8);
            *reinterpret_cast<s16x8*>(&Vs[r * 64 + cs * 8]) = vv;
        }

        // packed mask: lane lr's bit for key t*16+lr sits at (lr*4+t)
        unsigned mbits[4];
#pragma unroll
        for (int v = 0; v < 4; v++) {
            unsigned long long pw = Mp[mrow0 + (size_t)v * (NSEQ / 64) + (kv0 >> 6)];
            mbits[v] = (unsigned)(pw >> (lr * 4)) & 15u;
        }
        __syncthreads();

        // S = Q K^T (per wave: 16 q-rows x 64 keys), already in exp2 domain
        fx4 s[4];
#pragma unroll
        for (int t = 0; t < 4; t++) {
            s[t] = zero4();
#pragma unroll
            for (int kk = 0; kk < 2; kk++) {
                int r  = t * 16 + lr;
                int cu = kk * 4 + lg;
                int cs = cu ^ (r & 7);
                s16x8 kf = *reinterpret_cast<const s16x8*>(&Ks[r * 64 + cs * 8]);
                s[t] = __builtin_amdgcn_mfma_f32_16x16x32_bf16(qf[kk], kf, s[t], 0, 0, 0);
            }
        }

        // mask + online softmax (exp2 domain)
        float tmax[4];
#pragma unroll
        for (int v = 0; v < 4; v++) tmax[v] = -3.0e38f;
#pragma unroll
        for (int t = 0; t < 4; t++)
#pragma unroll
            for (int v = 0; v < 4; v++) {
                float sv = ((mbits[v] >> t) & 1u) ? -3.0e38f : s[t][v];
                s[t][v] = sv;
                tmax[v] = fmaxf(tmax[v], sv);
            }
#pragma unroll
        for (int off = 1; off < 16; off <<= 1)
#pragma unroll
            for (int v = 0; v < 4; v++)
                tmax[v] = fmaxf(tmax[v], __shfl_xor(tmax[v], off));

        float sc[4], psum[4];
#pragma unroll
        for (int v = 0; v < 4; v++) {
            float mn = fmaxf(mrow[v], tmax[v]);
            sc[v]    = exp2_fast(mrow[v] - mn);
            mrow[v]  = mn;
            psum[v]  = 0.f;
        }
#pragma unroll
        for (int t = 0; t < 4; t++)
#pragma unroll
            for (int v = 0; v < 4; v++) {
                float p = exp2_fast(s[t][v] - mrow[v]);
                s[t][v] = p;
                psum[v] += p;
            }
#pragma unroll
        for (int off = 1; off < 16; off <<= 1)
#pragma unroll
            for (int v = 0; v < 4; v++)
                psum[v] += __shfl_xor(psum[v], off);
#pragma unroll
        for (int v = 0; v < 4; v++) lrow[v] = lrow[v] * sc[v] + psum[v];
#pragma unroll
        for (int t = 0; t < 4; t++)
#pragma unroll
            for (int v = 0; v < 4; v++) acc[t][v] *= sc[v];

        // P -> LDS (A-fragment layout); wave-private rows, no barrier needed
#pragma unroll
        for (int t = 0; t < 4; t++)
#pragma unroll
            for (int v = 0; v < 4; v++)
                Ps[w][lg * 4 + v][t * 16 + lr] = f2bf(s[t][v]);

        // O += P V
#pragma unroll
        for (int kk = 0; kk < 2; kk++) {
            s16x8 pf = *reinterpret_cast<const s16x8*>(&Ps[w][lr][kk * 32 + 8 * lg]);
#pragma unroll
            for (int t = 0; t < 4; t++) {
                int r  = t * 16 + lr;
                int cu = kk * 4 + lg;
                int cs = cu ^ (r & 7);
                s16x8 vf = *reinterpret_cast<const s16x8*>(&Vs[r * 64 + cs * 8]);
                acc[t] = __builtin_amdgcn_mfma_f32_16x16x32_bf16(pf, vf, acc[t], 0, 0, 0);
            }
        }
    }

#pragma unroll
    for (int t = 0; t < 4; t++)
#pragma unroll
        for (int v = 0; v < 4; v++) {
            int q = qglob + v;
            int d = t * 16 + lr;
            Obuf[((size_t)b * NSEQ + q) * DM + h * DH + d] = acc[t][v] / lrow[v];
        }
}

// ---------------- launch ----------------
extern "C" void kernel_launch(void* const* d_in, const int* in_sizes, int n_in,
                              void* d_out, int out_size, void* d_ws, size_t ws_size,
                              hipStream_t stream) {
    const float* q    = (const float*)d_in[0];
    const void*  mask = (const void*)d_in[1];
    const float* Wq   = (const float*)d_in[2];
    const float* Wk   = (const float*)d_in[3];
    const float* Wv   = (const float*)d_in[4];
    const float* Wo   = (const float*)d_in[5];
    const float* bo   = (const float*)d_in[6];
    float* out = (float*)d_out;

    char* ws = (char*)d_ws;
    const size_t MB = 1024 * 1024;
    unsigned short* qbf  = (unsigned short*)(ws + 0);        // 8 MB  [4096][1024] (QKV phase)
    unsigned long long* packed = (unsigned long long*)(ws + 0); // 1 MB, reuses qbf AFTER gemm_qkv
    unsigned short* Wqb  = (unsigned short*)(ws + 8  * MB);  // 2 MB
    unsigned short* Wkb  = (unsigned short*)(ws + 10 * MB);  // 2 MB
    unsigned short* Wvb  = (unsigned short*)(ws + 12 * MB);  // 2 MB
    unsigned short* Wob  = (unsigned short*)(ws + 14 * MB);  // 2 MB
    unsigned short* Qh   = (unsigned short*)(ws + 16 * MB);  // 8 MB  [B,H,N,64]
    unsigned short* Kh   = (unsigned short*)(ws + 24 * MB);  // 8 MB  [B,H,N,64]
    unsigned short* VhT  = (unsigned short*)(ws + 32 * MB);  // 8 MB  [B,H,64,N]
    float*          Obuf = (float*)(ws + 40 * MB);           // 16 MB [B,N,1024] fp32
    int*            flag = (int*)(ws + 56 * MB);             // 4 B

    hipMemsetAsync(flag, 0, 4, stream);
    mask_detect<<<1024, 256, 0, stream>>>((const unsigned int*)mask, flag);

    cvt_kernel<<<4096, 256, 0, stream>>>(q, qbf, (2 * NSEQ * DM) / 4);
    // DM*DM/4 = 262144 float4s per matrix -> 1024 blocks of 256
    cvt4_kernel<<<dim3(1024, 4), 256, 0, stream>>>(Wq, Wk, Wv, Wo, Wqb, Wkb, Wvb, Wob);

    gemm_qkv<<<dim3(24, 32), 256, 0, stream>>>(qbf, Wqb, Wkb, Wvb, Qh, Kh, VhT);

    // qbf is dead now; pack the mask into its space (1 MB)
    mask_pack<<<1024, 256, 0, stream>>>(mask, flag, packed);

    attn_kernel<<<dim3(NSEQ / 64, 32), 256, 0, stream>>>(Qh, Kh, VhT, packed, Obuf);

    gemm_out<<<dim3(8, 32), 256, 0, stream>>>(Obuf, Wob, out, bo);
}

// Round 7
// 306.547 us; speedup vs baseline: 1.1074x; 1.0550x over previous
//
#include <hip/hip_runtime.h>
#include <hip/hip_bf16.h>

typedef float fx4 __attribute__((ext_vector_type(4)));
typedef short s16x8 __attribute__((ext_vector_type(8)));

#define NSEQ 2048
#define DM   1024
#define NH   16
#define DH   64
#define MROWS 4096               // B * NSEQ
#define NWORDS (2 * NSEQ * (NSEQ / 64))   // 131072 packed-mask words

// QK scale with log2(e) folded in: softmax runs in exp2 domain.
#define QK_SCALE (0.125f * 1.44269504088896f)

__device__ __forceinline__ unsigned short f2bf(float f) {
    union { float f; unsigned u; } c; c.f = f;
    unsigned u = c.u;
    unsigned r = u + 0x7FFFu + ((u >> 16) & 1u);   // round-to-nearest-even
    return (unsigned short)(r >> 16);
}

__device__ __forceinline__ float exp2_fast(float x) {
#if __has_builtin(__builtin_amdgcn_exp2f)
    return __builtin_amdgcn_exp2f(x);
#else
    return exp2f(x);
#endif
}

__device__ __forceinline__ fx4 zero4() {
    fx4 z; z[0] = 0.f; z[1] = 0.f; z[2] = 0.f; z[3] = 0.f; return z;
}

// async global->LDS, 16B per lane. LDS dest = wave-uniform base + lane*16.
__device__ __forceinline__ void gload16(const void* g, void* l) {
    __builtin_amdgcn_global_load_lds(
        (const __attribute__((address_space(1))) unsigned int*)g,
        (__attribute__((address_space(3))) unsigned int*)l,
        16, 0, 0);
}

// ---------------- fp32 -> bf16 conversion ----------------
__global__ void cvt_kernel(const float* __restrict__ in,
                           unsigned short* __restrict__ out, int n4) {
    int i = blockIdx.x * blockDim.x + threadIdx.x;
    if (i >= n4) return;
    float4 v = reinterpret_cast<const float4*>(in)[i];
    ushort4 o;
    o.x = f2bf(v.x); o.y = f2bf(v.y); o.z = f2bf(v.z); o.w = f2bf(v.w);
    reinterpret_cast<ushort4*>(out)[i] = o;
}

// 4 weight matrices in one launch; grid MUST be (1024, 4): DM*DM/4/256 = 1024.
__global__ void cvt4_kernel(const float* __restrict__ w0, const float* __restrict__ w1,
                            const float* __restrict__ w2, const float* __restrict__ w3,
                            unsigned short* __restrict__ o0, unsigned short* __restrict__ o1,
                            unsigned short* __restrict__ o2, unsigned short* __restrict__ o3) {
    const float* in; unsigned short* out;
    switch (blockIdx.y) {
        case 0:  in = w0; out = o0; break;
        case 1:  in = w1; out = o1; break;
        case 2:  in = w2; out = o2; break;
        default: in = w3; out = o3; break;
    }
    int i = blockIdx.x * blockDim.x + threadIdx.x;
    float4 v = reinterpret_cast<const float4*>(in)[i];
    ushort4 o;
    o.x = f2bf(v.x); o.y = f2bf(v.y); o.z = f2bf(v.z); o.w = f2bf(v.w);
    reinterpret_cast<ushort4*>(out)[i] = o;
}

// ---------------- mask dtype detection ----------------
// int32 0/1 data can never make a u32 word > 1; packed bool bytes will.
__global__ void mask_detect(const unsigned int* __restrict__ m, int* __restrict__ flag) {
    unsigned mx = 0;
    int stride = gridDim.x * blockDim.x;
    for (int i = blockIdx.x * blockDim.x + threadIdx.x; i < (2 * NSEQ * NSEQ) / 4; i += stride) {
        unsigned v = m[i];
        mx = v > mx ? v : mx;
    }
    if (__any(mx > 1u)) {
        if ((threadIdx.x & 63) == 0) atomicOr(flag, 1);
    }
}

// ---------------- mask bit-pack ----------------
// packed[w] covers keys kw*64..+63 of global row bq (w = bq*32 + kw).
// Bit position p holds key (p&3)*16 + (p>>2): attn lane lr extracts its
// 4 bits (t=0..3) with one >> (lr*4).
__global__ void mask_pack(const void* __restrict__ mask, const int* __restrict__ mflag,
                          unsigned long long* __restrict__ packed) {
    const int flg  = mflag[0];
    const int lane = threadIdx.x & 63;
    const int wpb  = blockDim.x >> 6;
    const int perm = (lane & 3) * 16 + (lane >> 2);
    size_t w = (size_t)blockIdx.x * wpb + (threadIdx.x >> 6);
    const size_t stride = (size_t)gridDim.x * wpb;
    for (; w < NWORDS; w += stride) {
        size_t elem = (w >> 5) * (size_t)NSEQ + (size_t)(w & 31) * 64 + perm;
        int mv = flg ? (int)((const unsigned char*)mask)[elem]
                     : ((const int*)mask)[elem];
        unsigned long long bits = __ballot(mv != 0);
        if (lane == 0) packed[w] = bits;
    }
}

// ---------------- fused QKV GEMM (m97 staging: global_load_lds, linear LDS) ----
// grid (24, 32): blockIdx.x>>3 selects segment (0=Q,1=K,2=V).
// C[m][c] = sum_k A[m][k] * W[c][k]; 128x128 tile, 4 waves, BK=32.
// LDS tile [128][32] shorts: row = 64B = FOUR 16B chunks -> chunk j maps to
// row j>>2, short-offset (j&3)*8.
__global__ __launch_bounds__(256) void gemm_qkv(
        const unsigned short* __restrict__ A,
        const unsigned short* __restrict__ Wq,
        const unsigned short* __restrict__ Wk,
        const unsigned short* __restrict__ Wv,
        unsigned short* __restrict__ Qh,     // [B,H,N,64], pre-scaled by QK_SCALE
        unsigned short* __restrict__ Kh,     // [B,H,N,64]
        unsigned short* __restrict__ VhT) {  // [B,H,64,N]
    __shared__ unsigned short As[128 * 32];  // linear (gload_lds requires it)
    __shared__ unsigned short Bs[128 * 32];

    const int tid  = threadIdx.x;
    const int lane = tid & 63;
    const int w    = tid >> 6;
    const int lr   = lane & 15;
    const int lg   = lane >> 4;
    const int wr   = (w >> 1) * 64;
    const int wc   = (w & 1) * 64;
    const int rowbase = blockIdx.y * 128;
    const int seg     = blockIdx.x >> 3;              // 0,1,2
    const int cb      = (blockIdx.x & 7) * 128;       // col base within segment
    const unsigned short* W = seg == 0 ? Wq : (seg == 1 ? Wk : Wv);
    const float scale = seg == 0 ? QK_SCALE : 1.0f;

    fx4 acc[4][4];
#pragma unroll
    for (int i = 0; i < 4; i++)
#pragma unroll
        for (int j = 0; j < 4; j++) acc[i][j] = zero4();

    for (int k0 = 0; k0 < DM; k0 += 32) {
        __syncthreads();
        // stage 128x32: chunk j (16B) = row j>>2, shorts (j&3)*8..+8
#pragma unroll
        for (int i = 0; i < 2; i++) {
            int j = i * 256 + w * 64 + lane;
            int r = j >> 2, c8 = (j & 3) * 8;
            gload16(A + (size_t)(rowbase + r) * DM + k0 + c8,
                    As + (size_t)(i * 256 + w * 64) * 8);
            gload16(W + (size_t)(cb + r) * DM + k0 + c8,
                    Bs + (size_t)(i * 256 + w * 64) * 8);
        }
        __syncthreads();   // compiler drains vmcnt before s_barrier

        s16x8 af[4], bf[4];
#pragma unroll
        for (int mi = 0; mi < 4; mi++)
            af[mi] = *reinterpret_cast<const s16x8*>(&As[(wr + mi * 16 + lr) * 32 + 8 * lg]);
#pragma unroll
        for (int ni = 0; ni < 4; ni++)
            bf[ni] = *reinterpret_cast<const s16x8*>(&Bs[(wc + ni * 16 + lr) * 32 + 8 * lg]);
#pragma unroll
        for (int mi = 0; mi < 4; mi++)
#pragma unroll
            for (int ni = 0; ni < 4; ni++)
                acc[mi][ni] = __builtin_amdgcn_mfma_f32_16x16x32_bf16(af[mi], bf[ni], acc[mi][ni], 0, 0, 0);
    }

#pragma unroll
    for (int mi = 0; mi < 4; mi++) {
#pragma unroll
        for (int ni = 0; ni < 4; ni++) {
#pragma unroll
            for (int v = 0; v < 4; v++) {
                int m    = rowbase + wr + mi * 16 + lg * 4 + v;
                int cseg = cb + wc + ni * 16 + lr;
                float val = acc[mi][ni][v] * scale;
                int b = m >> 11, nseq = m & 2047;
                int h = cseg >> 6, dh = cseg & 63;
                if (seg < 2) {
                    unsigned short* dst = seg == 0 ? Qh : Kh;
                    dst[((size_t)(b * NH + h) * NSEQ + nseq) * DH + dh] = f2bf(val);
                } else {
                    VhT[((size_t)(b * NH + h) * DH + dh) * NSEQ + nseq] = f2bf(val);
                }
            }
        }
    }
}

// ---------------- output GEMM (bf16 A via gload_lds, +bias, fp32 out) --------
__global__ __launch_bounds__(256) void gemm_out(
        const unsigned short* __restrict__ A,    // Obuf bf16 [4096][1024]
        const unsigned short* __restrict__ W,
        float* __restrict__ out,
        const float* __restrict__ bias) {
    __shared__ unsigned short As[128 * 32];
    __shared__ unsigned short Bs[128 * 32];

    const int tid  = threadIdx.x;
    const int lane = tid & 63;
    const int w    = tid >> 6;
    const int lr   = lane & 15;
    const int lg   = lane >> 4;
    const int wr   = (w >> 1) * 64;
    const int wc   = (w & 1) * 64;
    const int rowbase = blockIdx.y * 128;
    const int colbase = blockIdx.x * 128;

    fx4 acc[4][4];
#pragma unroll
    for (int i = 0; i < 4; i++)
#pragma unroll
        for (int j = 0; j < 4; j++) acc[i][j] = zero4();

    for (int k0 = 0; k0 < DM; k0 += 32) {
        __syncthreads();
#pragma unroll
        for (int i = 0; i < 2; i++) {
            int j = i * 256 + w * 64 + lane;
            int r = j >> 2, c8 = (j & 3) * 8;
            gload16(A + (size_t)(rowbase + r) * DM + k0 + c8,
                    As + (size_t)(i * 256 + w * 64) * 8);
            gload16(W + (size_t)(colbase + r) * DM + k0 + c8,
                    Bs + (size_t)(i * 256 + w * 64) * 8);
        }
        __syncthreads();

        s16x8 af[4], bf[4];
#pragma unroll
        for (int mi = 0; mi < 4; mi++)
            af[mi] = *reinterpret_cast<const s16x8*>(&As[(wr + mi * 16 + lr) * 32 + 8 * lg]);
#pragma unroll
        for (int ni = 0; ni < 4; ni++)
            bf[ni] = *reinterpret_cast<const s16x8*>(&Bs[(wc + ni * 16 + lr) * 32 + 8 * lg]);
#pragma unroll
        for (int mi = 0; mi < 4; mi++)
#pragma unroll
            for (int ni = 0; ni < 4; ni++)
                acc[mi][ni] = __builtin_amdgcn_mfma_f32_16x16x32_bf16(af[mi], bf[ni], acc[mi][ni], 0, 0, 0);
    }

#pragma unroll
    for (int mi = 0; mi < 4; mi++)
#pragma unroll
        for (int ni = 0; ni < 4; ni++)
#pragma unroll
            for (int v = 0; v < 4; v++) {
                int m = rowbase + wr + mi * 16 + lg * 4 + v;
                int c = colbase + wc + ni * 16 + lr;
                out[(size_t)m * DM + c] = acc[mi][ni][v] + bias[c];
            }
}

// ---------------- flash attention ----------------
// grid: x = N/64 q-tiles, y = B*H. 4 waves; wave w owns q rows w*16..+15.
__global__ __launch_bounds__(256) void attn_kernel(
        const unsigned short* __restrict__ Qh,   // [B,H,N,64] bf16 (scaled by QK_SCALE)
        const unsigned short* __restrict__ Kh,   // [B,H,N,64] bf16
        const unsigned short* __restrict__ VhT,  // [B,H,64,N] bf16
        const unsigned long long* __restrict__ Mp, // packed mask [B*N][32]
        unsigned short* __restrict__ Obuf) {     // [B,N,1024] bf16
    __shared__ unsigned short Ks[64 * 64];       // XOR-swizzled rows
    __shared__ unsigned short Vs[64 * 64];       // XOR-swizzled rows (V^T: row=d, col=key)
    __shared__ unsigned short Ps[4][16][72];     // per-wave P tile: 16 q x 64 keys

    const int tid  = threadIdx.x;
    const int lane = tid & 63;
    const int w    = tid >> 6;
    const int lr   = lane & 15;
    const int lg   = lane >> 4;
    const int qbase = blockIdx.x * 64;
    const int bh    = blockIdx.y;
    const int b     = bh >> 4;
    const int h     = bh & 15;

    s16x8 qf[2];
    const size_t qrow0 = (size_t)bh * NSEQ + qbase + w * 16 + lr;
#pragma unroll
    for (int kk = 0; kk < 2; kk++)
        qf[kk] = *reinterpret_cast<const s16x8*>(Qh + qrow0 * DH + kk * 32 + 8 * lg);

    float mrow[4], lrow[4];
    fx4 acc[4];
#pragma unroll
    for (int v = 0; v < 4; v++) { mrow[v] = -3.0e38f; lrow[v] = 0.f; }
#pragma unroll
    for (int t = 0; t < 4; t++) acc[t] = zero4();

    const int qglob = qbase + w * 16 + lg * 4;   // first of this lane's 4 q rows
    const size_t mrow0 = ((size_t)b * NSEQ + qglob) * (NSEQ / 64);

    for (int kv0 = 0; kv0 < NSEQ; kv0 += 64) {
        __syncthreads();
#pragma unroll
        for (int i = 0; i < 2; i++) {
            int u  = tid + i * 256;
            int r  = u >> 3, cu = u & 7;
            int cs = cu ^ (r & 7);
            s16x8 kv = *reinterpret_cast<const s16x8*>(Kh + ((size_t)bh * NSEQ + kv0 + r) * DH + cu * 8);
            *reinterpret_cast<s16x8*>(&Ks[r * 64 + cs * 8]) = kv;
            s16x8 vv = *reinterpret_cast<const s16x8*>(VhT + ((size_t)bh * DH + r) * NSEQ + kv0 + cu * 8);
            *reinterpret_cast<s16x8*>(&Vs[r * 64 + cs * 8]) = vv;
        }

        // packed mask: lane lr's bit for key t*16+lr sits at (lr*4+t)
        unsigned mbits[4];
#pragma unroll
        for (int v = 0; v < 4; v++) {
            unsigned long long pw = Mp[mrow0 + (size_t)v * (NSEQ / 64) + (kv0 >> 6)];
            mbits[v] = (unsigned)(pw >> (lr * 4)) & 15u;
        }
        __syncthreads();

        // S = Q K^T (per wave: 16 q-rows x 64 keys), already in exp2 domain
        fx4 s[4];
#pragma unroll
        for (int t = 0; t < 4; t++) {
            s[t] = zero4();
#pragma unroll
            for (int kk = 0; kk < 2; kk++) {
                int r  = t * 16 + lr;
                int cu = kk * 4 + lg;
                int cs = cu ^ (r & 7);
                s16x8 kf = *reinterpret_cast<const s16x8*>(&Ks[r * 64 + cs * 8]);
                s[t] = __builtin_amdgcn_mfma_f32_16x16x32_bf16(qf[kk], kf, s[t], 0, 0, 0);
            }
        }

        // mask + online softmax (exp2 domain)
        float tmax[4];
#pragma unroll
        for (int v = 0; v < 4; v++) tmax[v] = -3.0e38f;
#pragma unroll
        for (int t = 0; t < 4; t++)
#pragma unroll
            for (int v = 0; v < 4; v++) {
                float sv = ((mbits[v] >> t) & 1u) ? -3.0e38f : s[t][v];
                s[t][v] = sv;
                tmax[v] = fmaxf(tmax[v], sv);
            }
#pragma unroll
        for (int off = 1; off < 16; off <<= 1)
#pragma unroll
            for (int v = 0; v < 4; v++)
                tmax[v] = fmaxf(tmax[v], __shfl_xor(tmax[v], off));

        float sc[4], psum[4];
#pragma unroll
        for (int v = 0; v < 4; v++) {
            float mn = fmaxf(mrow[v], tmax[v]);
            sc[v]    = exp2_fast(mrow[v] - mn);
            mrow[v]  = mn;
            psum[v]  = 0.f;
        }
#pragma unroll
        for (int t = 0; t < 4; t++)
#pragma unroll
            for (int v = 0; v < 4; v++) {
                float p = exp2_fast(s[t][v] - mrow[v]);
                s[t][v] = p;
                psum[v] += p;
            }
#pragma unroll
        for (int off = 1; off < 16; off <<= 1)
#pragma unroll
            for (int v = 0; v < 4; v++)
                psum[v] += __shfl_xor(psum[v], off);
#pragma unroll
        for (int v = 0; v < 4; v++) lrow[v] = lrow[v] * sc[v] + psum[v];
#pragma unroll
        for (int t = 0; t < 4; t++)
#pragma unroll
            for (int v = 0; v < 4; v++) acc[t][v] *= sc[v];

        // P -> LDS (A-fragment layout); wave-private rows, no barrier needed
#pragma unroll
        for (int t = 0; t < 4; t++)
#pragma unroll
            for (int v = 0; v < 4; v++)
                Ps[w][lg * 4 + v][t * 16 + lr] = f2bf(s[t][v]);

        // O += P V
#pragma unroll
        for (int kk = 0; kk < 2; kk++) {
            s16x8 pf = *reinterpret_cast<const s16x8*>(&Ps[w][lr][kk * 32 + 8 * lg]);
#pragma unroll
            for (int t = 0; t < 4; t++) {
                int r  = t * 16 + lr;
                int cu = kk * 4 + lg;
                int cs = cu ^ (r & 7);
                s16x8 vf = *reinterpret_cast<const s16x8*>(&Vs[r * 64 + cs * 8]);
                acc[t] = __builtin_amdgcn_mfma_f32_16x16x32_bf16(pf, vf, acc[t], 0, 0, 0);
            }
        }
    }

#pragma unroll
    for (int t = 0; t < 4; t++)
#pragma unroll
        for (int v = 0; v < 4; v++) {
            int q = qglob + v;
            int d = t * 16 + lr;
            Obuf[((size_t)b * NSEQ + q) * DM + h * DH + d] = f2bf(acc[t][v] / lrow[v]);
        }
}

// ---------------- launch ----------------
extern "C" void kernel_launch(void* const* d_in, const int* in_sizes, int n_in,
                              void* d_out, int out_size, void* d_ws, size_t ws_size,
                              hipStream_t stream) {
    const float* q    = (const float*)d_in[0];
    const void*  mask = (const void*)d_in[1];
    const float* Wq   = (const float*)d_in[2];
    const float* Wk   = (const float*)d_in[3];
    const float* Wv   = (const float*)d_in[4];
    const float* Wo   = (const float*)d_in[5];
    const float* bo   = (const float*)d_in[6];
    float* out = (float*)d_out;

    char* ws = (char*)d_ws;
    const size_t MB = 1024 * 1024;
    unsigned short* qbf  = (unsigned short*)(ws + 0);        // 8 MB (QKV phase)
    unsigned long long* packed = (unsigned long long*)(ws + 0); // 1 MB, reuses qbf AFTER gemm_qkv
    unsigned short* Wqb  = (unsigned short*)(ws + 8  * MB);  // 2 MB
    unsigned short* Wkb  = (unsigned short*)(ws + 10 * MB);  // 2 MB
    unsigned short* Wvb  = (unsigned short*)(ws + 12 * MB);  // 2 MB
    unsigned short* Wob  = (unsigned short*)(ws + 14 * MB);  // 2 MB
    unsigned short* Qh   = (unsigned short*)(ws + 16 * MB);  // 8 MB  [B,H,N,64]
    unsigned short* Kh   = (unsigned short*)(ws + 24 * MB);  // 8 MB  [B,H,N,64]
    unsigned short* VhT  = (unsigned short*)(ws + 32 * MB);  // 8 MB  [B,H,64,N]
    unsigned short* Obuf = (unsigned short*)(ws + 40 * MB);  // 8 MB  [B,N,1024] bf16
    int*            flag = (int*)(ws + 56 * MB);             // 4 B

    hipMemsetAsync(flag, 0, 4, stream);
    mask_detect<<<1024, 256, 0, stream>>>((const unsigned int*)mask, flag);

    cvt_kernel<<<4096, 256, 0, stream>>>(q, qbf, (2 * NSEQ * DM) / 4);
    cvt4_kernel<<<dim3(1024, 4), 256, 0, stream>>>(Wq, Wk, Wv, Wo, Wqb, Wkb, Wvb, Wob);

    gemm_qkv<<<dim3(24, 32), 256, 0, stream>>>(qbf, Wqb, Wkb, Wvb, Qh, Kh, VhT);

    // qbf is dead now; pack the mask into its space (1 MB)
    mask_pack<<<1024, 256, 0, stream>>>(mask, flag, packed);

    attn_kernel<<<dim3(NSEQ / 64, 32), 256, 0, stream>>>(Qh, Kh, VhT, packed, Obuf);

    gemm_out<<<dim3(8, 32), 256, 0, stream>>>(Obuf, Wob, out, bo);
}

// Round 8
// 258.496 us; speedup vs baseline: 1.3133x; 1.1859x over previous
//
#include <hip/hip_runtime.h>
#include <hip/hip_bf16.h>

typedef float fx4 __attribute__((ext_vector_type(4)));
typedef short s16x8 __attribute__((ext_vector_type(8)));

#define NSEQ 2048
#define DM   1024
#define NH   16
#define DH   64
#define MROWS 4096               // B * NSEQ
#define NWORDS (2 * NSEQ * (NSEQ / 64))   // 131072 packed-mask words

// QK scale with log2(e) folded in: softmax runs in exp2 domain.
#define QK_SCALE (0.125f * 1.44269504088896f)

__device__ __forceinline__ unsigned short f2bf(float f) {
    union { float f; unsigned u; } c; c.f = f;
    unsigned u = c.u;
    unsigned r = u + 0x7FFFu + ((u >> 16) & 1u);   // round-to-nearest-even
    return (unsigned short)(r >> 16);
}

__device__ __forceinline__ float exp2_fast(float x) {
#if __has_builtin(__builtin_amdgcn_exp2f)
    return __builtin_amdgcn_exp2f(x);
#else
    return exp2f(x);
#endif
}

// hardware packed f32->bf16 (RNE): dst.lo = bf16(a), dst.hi = bf16(b)
__device__ __forceinline__ unsigned cvt_pk_bf16(float a, float b) {
    unsigned r;
    asm("v_cvt_pk_bf16_f32 %0, %1, %2" : "=v"(r) : "v"(a), "v"(b));
    return r;
}

__device__ __forceinline__ fx4 zero4() {
    fx4 z; z[0] = 0.f; z[1] = 0.f; z[2] = 0.f; z[3] = 0.f; return z;
}

// async global->LDS, 16B per lane. LDS dest = wave-uniform base + lane*16.
__device__ __forceinline__ void gload16(const void* g, void* l) {
    __builtin_amdgcn_global_load_lds(
        (const __attribute__((address_space(1))) unsigned int*)g,
        (__attribute__((address_space(3))) unsigned int*)l,
        16, 0, 0);
}

// ---------------- fp32 -> bf16 conversion ----------------
__global__ void cvt_kernel(const float* __restrict__ in,
                           unsigned short* __restrict__ out, int n4) {
    int i = blockIdx.x * blockDim.x + threadIdx.x;
    if (i >= n4) return;
    float4 v = reinterpret_cast<const float4*>(in)[i];
    ushort4 o;
    o.x = f2bf(v.x); o.y = f2bf(v.y); o.z = f2bf(v.z); o.w = f2bf(v.w);
    reinterpret_cast<ushort4*>(out)[i] = o;
}

// 4 weight matrices in one launch; grid MUST be (1024, 4): DM*DM/4/256 = 1024.
__global__ void cvt4_kernel(const float* __restrict__ w0, const float* __restrict__ w1,
                            const float* __restrict__ w2, const float* __restrict__ w3,
                            unsigned short* __restrict__ o0, unsigned short* __restrict__ o1,
                            unsigned short* __restrict__ o2, unsigned short* __restrict__ o3) {
    const float* in; unsigned short* out;
    switch (blockIdx.y) {
        case 0:  in = w0; out = o0; break;
        case 1:  in = w1; out = o1; break;
        case 2:  in = w2; out = o2; break;
        default: in = w3; out = o3; break;
    }
    int i = blockIdx.x * blockDim.x + threadIdx.x;
    float4 v = reinterpret_cast<const float4*>(in)[i];
    ushort4 o;
    o.x = f2bf(v.x); o.y = f2bf(v.y); o.z = f2bf(v.z); o.w = f2bf(v.w);
    reinterpret_cast<ushort4*>(out)[i] = o;
}

// ---------------- mask dtype detection ----------------
// int32 0/1 data can never make a u32 word > 1; packed bool bytes will.
__global__ void mask_detect(const unsigned int* __restrict__ m, int* __restrict__ flag) {
    unsigned mx = 0;
    int stride = gridDim.x * blockDim.x;
    for (int i = blockIdx.x * blockDim.x + threadIdx.x; i < (2 * NSEQ * NSEQ) / 4; i += stride) {
        unsigned v = m[i];
        mx = v > mx ? v : mx;
    }
    if (__any(mx > 1u)) {
        if ((threadIdx.x & 63) == 0) atomicOr(flag, 1);
    }
}

// ---------------- mask bit-pack ----------------
// packed[w] covers keys kw*64..+63 of global row bq (w = bq*32 + kw).
// Bit p <-> key ((p>>2)&3)*16 + ((p>>4)&3)*4 + (p&3): attn lane (lg,lr)
// finds its 16 bits (keys t*16+lg*4+v) contiguously at p = lg*16 + t*4 + v.
__global__ void mask_pack(const void* __restrict__ mask, const int* __restrict__ mflag,
                          unsigned long long* __restrict__ packed) {
    const int flg  = mflag[0];
    const int lane = threadIdx.x & 63;
    const int wpb  = blockDim.x >> 6;
    const int perm = ((lane >> 2) & 3) * 16 + ((lane >> 4) & 3) * 4 + (lane & 3);
    size_t w = (size_t)blockIdx.x * wpb + (threadIdx.x >> 6);
    const size_t stride = (size_t)gridDim.x * wpb;
    for (; w < NWORDS; w += stride) {
        size_t elem = (w >> 5) * (size_t)NSEQ + (size_t)(w & 31) * 64 + perm;
        int mv = flg ? (int)((const unsigned char*)mask)[elem]
                     : ((const int*)mask)[elem];
        unsigned long long bits = __ballot(mv != 0);
        if (lane == 0) packed[w] = bits;
    }
}

// ---------------- fused QKV GEMM (m97 staging) ----------------
__global__ __launch_bounds__(256) void gemm_qkv(
        const unsigned short* __restrict__ A,
        const unsigned short* __restrict__ Wq,
        const unsigned short* __restrict__ Wk,
        const unsigned short* __restrict__ Wv,
        unsigned short* __restrict__ Qh,     // [B,H,N,64], pre-scaled by QK_SCALE
        unsigned short* __restrict__ Kh,     // [B,H,N,64]
        unsigned short* __restrict__ VhT) {  // [B,H,64,N]
    __shared__ unsigned short As[128 * 32];
    __shared__ unsigned short Bs[128 * 32];

    const int tid  = threadIdx.x;
    const int lane = tid & 63;
    const int w    = tid >> 6;
    const int lr   = lane & 15;
    const int lg   = lane >> 4;
    const int wr   = (w >> 1) * 64;
    const int wc   = (w & 1) * 64;
    const int rowbase = blockIdx.y * 128;
    const int seg     = blockIdx.x >> 3;              // 0,1,2
    const int cb      = (blockIdx.x & 7) * 128;
    const unsigned short* W = seg == 0 ? Wq : (seg == 1 ? Wk : Wv);
    const float scale = seg == 0 ? QK_SCALE : 1.0f;

    fx4 acc[4][4];
#pragma unroll
    for (int i = 0; i < 4; i++)
#pragma unroll
        for (int j = 0; j < 4; j++) acc[i][j] = zero4();

    for (int k0 = 0; k0 < DM; k0 += 32) {
        __syncthreads();
#pragma unroll
        for (int i = 0; i < 2; i++) {
            int j = i * 256 + w * 64 + lane;
            int r = j >> 2, c8 = (j & 3) * 8;
            gload16(A + (size_t)(rowbase + r) * DM + k0 + c8,
                    As + (size_t)(i * 256 + w * 64) * 8);
            gload16(W + (size_t)(cb + r) * DM + k0 + c8,
                    Bs + (size_t)(i * 256 + w * 64) * 8);
        }
        __syncthreads();

        s16x8 af[4], bf[4];
#pragma unroll
        for (int mi = 0; mi < 4; mi++)
            af[mi] = *reinterpret_cast<const s16x8*>(&As[(wr + mi * 16 + lr) * 32 + 8 * lg]);
#pragma unroll
        for (int ni = 0; ni < 4; ni++)
            bf[ni] = *reinterpret_cast<const s16x8*>(&Bs[(wc + ni * 16 + lr) * 32 + 8 * lg]);
#pragma unroll
        for (int mi = 0; mi < 4; mi++)
#pragma unroll
            for (int ni = 0; ni < 4; ni++)
                acc[mi][ni] = __builtin_amdgcn_mfma_f32_16x16x32_bf16(af[mi], bf[ni], acc[mi][ni], 0, 0, 0);
    }

#pragma unroll
    for (int mi = 0; mi < 4; mi++) {
#pragma unroll
        for (int ni = 0; ni < 4; ni++) {
#pragma unroll
            for (int v = 0; v < 4; v++) {
                int m    = rowbase + wr + mi * 16 + lg * 4 + v;
                int cseg = cb + wc + ni * 16 + lr;
                float val = acc[mi][ni][v] * scale;
                int b = m >> 11, nseq = m & 2047;
                int h = cseg >> 6, dh = cseg & 63;
                if (seg < 2) {
                    unsigned short* dst = seg == 0 ? Qh : Kh;
                    dst[((size_t)(b * NH + h) * NSEQ + nseq) * DH + dh] = f2bf(val);
                } else {
                    VhT[((size_t)(b * NH + h) * DH + dh) * NSEQ + nseq] = f2bf(val);
                }
            }
        }
    }
}

// ---------------- output GEMM (bf16 A via gload_lds, +bias, fp32 out) --------
__global__ __launch_bounds__(256) void gemm_out(
        const unsigned short* __restrict__ A,    // Obuf bf16 [4096][1024]
        const unsigned short* __restrict__ W,
        float* __restrict__ out,
        const float* __restrict__ bias) {
    __shared__ unsigned short As[128 * 32];
    __shared__ unsigned short Bs[128 * 32];

    const int tid  = threadIdx.x;
    const int lane = tid & 63;
    const int w    = tid >> 6;
    const int lr   = lane & 15;
    const int lg   = lane >> 4;
    const int wr   = (w >> 1) * 64;
    const int wc   = (w & 1) * 64;
    const int rowbase = blockIdx.y * 128;
    const int colbase = blockIdx.x * 128;

    fx4 acc[4][4];
#pragma unroll
    for (int i = 0; i < 4; i++)
#pragma unroll
        for (int j = 0; j < 4; j++) acc[i][j] = zero4();

    for (int k0 = 0; k0 < DM; k0 += 32) {
        __syncthreads();
#pragma unroll
        for (int i = 0; i < 2; i++) {
            int j = i * 256 + w * 64 + lane;
            int r = j >> 2, c8 = (j & 3) * 8;
            gload16(A + (size_t)(rowbase + r) * DM + k0 + c8,
                    As + (size_t)(i * 256 + w * 64) * 8);
            gload16(W + (size_t)(colbase + r) * DM + k0 + c8,
                    Bs + (size_t)(i * 256 + w * 64) * 8);
        }
        __syncthreads();

        s16x8 af[4], bf[4];
#pragma unroll
        for (int mi = 0; mi < 4; mi++)
            af[mi] = *reinterpret_cast<const s16x8*>(&As[(wr + mi * 16 + lr) * 32 + 8 * lg]);
#pragma unroll
        for (int ni = 0; ni < 4; ni++)
            bf[ni] = *reinterpret_cast<const s16x8*>(&Bs[(wc + ni * 16 + lr) * 32 + 8 * lg]);
#pragma unroll
        for (int mi = 0; mi < 4; mi++)
#pragma unroll
            for (int ni = 0; ni < 4; ni++)
                acc[mi][ni] = __builtin_amdgcn_mfma_f32_16x16x32_bf16(af[mi], bf[ni], acc[mi][ni], 0, 0, 0);
    }

#pragma unroll
    for (int mi = 0; mi < 4; mi++)
#pragma unroll
        for (int ni = 0; ni < 4; ni++)
#pragma unroll
            for (int v = 0; v < 4; v++) {
                int m = rowbase + wr + mi * 16 + lg * 4 + v;
                int c = colbase + wc + ni * 16 + lr;
                out[(size_t)m * DM + c] = acc[mi][ni][v] + bias[c];
            }
}

// ---------------- flash attention (swapped QK^T, in-register softmax) --------
// 1024 blocks (XCD-swizzled), 4 waves; wave w owns q rows w*16..+15.
// Swapped MFMA: s[t][v] = S[q = w*16+lr][key = t*16+lg*4+v] -> softmax per-lane.
__global__ __launch_bounds__(256) void attn_kernel(
        const unsigned short* __restrict__ Qh,   // [B,H,N,64] bf16 (scaled by QK_SCALE)
        const unsigned short* __restrict__ Kh,   // [B,H,N,64] bf16
        const unsigned short* __restrict__ VhT,  // [B,H,64,N] bf16
        const unsigned long long* __restrict__ Mp, // packed mask [B*N][32]
        unsigned short* __restrict__ Obuf) {     // [B,N,1024] bf16
    __shared__ unsigned short Ks[2][64 * 64];    // XOR-swizzled rows, double-buffered
    __shared__ unsigned short Vs[2][64 * 64];    // V^T rows (row=d), swizzled, dbuf
    __shared__ __align__(16) unsigned int Ps[4][16 * 32]; // P bf16-pairs, XOR-swz

    const int tid  = threadIdx.x;
    const int lane = tid & 63;
    const int w    = tid >> 6;
    const int lr   = lane & 15;
    const int lg   = lane >> 4;

    // bijective XCD swizzle: 1024 = 8 XCDs x 128 contiguous blocks
    const int wg    = ((blockIdx.x & 7) << 7) + (blockIdx.x >> 3);
    const int qbase = (wg & 31) << 6;            // 32 q-tiles of 64
    const int bh    = wg >> 5;                   // 0..31
    const int b     = bh >> 4;
    const int h     = bh & 15;

    // Q fragment (B-operand): lane holds Q[q = w*16+lr][k = kk*32+8lg..+8]
    s16x8 qf[2];
    const size_t qrow = (size_t)bh * NSEQ + qbase + w * 16 + lr;
#pragma unroll
    for (int kk = 0; kk < 2; kk++)
        qf[kk] = *reinterpret_cast<const s16x8*>(Qh + qrow * DH + kk * 32 + 8 * lg);

    float mreg = -3.0e38f, lrow = 0.f;
    fx4 acc[4];
#pragma unroll
    for (int t = 0; t < 4; t++) acc[t] = zero4();

    const size_t mbase = ((size_t)b * NSEQ + qbase + w * 16 + lr) * (NSEQ / 64);

    // stage tile kv into buffer d: linear LDS dest + inverse-swizzled source
    auto stage = [&](int d, int kv0) {
#pragma unroll
        for (int i = 0; i < 2; i++) {
            int u  = i * 256 + w * 64 + lane;    // dest chunk 0..511
            int r  = u >> 3, cs = u & 7;
            int cu = cs ^ (r & 7);
            gload16(Kh + ((size_t)bh * NSEQ + kv0 + r) * DH + cu * 8,
                    &Ks[d][(size_t)(i * 256 + w * 64) * 8]);
            gload16(VhT + ((size_t)bh * DH + r) * NSEQ + kv0 + cu * 8,
                    &Vs[d][(size_t)(i * 256 + w * 64) * 8]);
        }
    };

    stage(0, 0);
    __syncthreads();

    for (int it = 0; it < NSEQ / 64; it++) {
        const int cur = it & 1;
        if (it < NSEQ / 64 - 1) stage(cur ^ 1, (it + 1) << 6);   // prefetch next

        // this lane's 16 mask bits (its q-row, keys t*16+lg*4+v at bit t*4+v)
        unsigned long long pwm = Mp[mbase + it];
        unsigned mb = (unsigned)((pwm >> (lg * 16)) & 0xFFFFull);

        // S^T = K · Q^T : 8 MFMAs
        fx4 s[4];
#pragma unroll
        for (int t = 0; t < 4; t++) {
            s[t] = zero4();
#pragma unroll
            for (int kk = 0; kk < 2; kk++) {
                int r  = t * 16 + lr;
                int cs = (kk * 4 + lg) ^ (r & 7);
                s16x8 kf = *reinterpret_cast<const s16x8*>(&Ks[cur][r * 64 + cs * 8]);
                s[t] = __builtin_amdgcn_mfma_f32_16x16x32_bf16(kf, qf[kk], s[t], 0, 0, 0);
            }
        }

        // mask + in-register max over this lane's 16 keys
        float tmax = -3.0e38f;
#pragma unroll
        for (int t = 0; t < 4; t++)
#pragma unroll
            for (int v = 0; v < 4; v++) {
                float sv = (mb & (1u << (t * 4 + v))) ? -3.0e38f : s[t][v];
                s[t][v] = sv;
                tmax = fmaxf(tmax, sv);
            }
        tmax = fmaxf(tmax, __shfl_xor(tmax, 16));
        tmax = fmaxf(tmax, __shfl_xor(tmax, 32));

        // defer-max: rescale only when the row max grows by > 8 (exp2 domain)
        if (__any(tmax > mreg + 8.0f)) {
            float mn = fmaxf(mreg, tmax);
            float sc = exp2_fast(mreg - mn);
            mreg = mn;
            lrow *= sc;
#pragma unroll
            for (int v = 0; v < 4; v++) {
                float scv = __shfl(sc, (lane & 48) | (lg * 4 + v));
#pragma unroll
                for (int t = 0; t < 4; t++) acc[t][v] *= scv;
            }
        }

        // exp2 + row sum (in-register + 2 shfl)
        float psum = 0.f;
#pragma unroll
        for (int t = 0; t < 4; t++)
#pragma unroll
            for (int v = 0; v < 4; v++) {
                float p = exp2_fast(s[t][v] - mreg);
                s[t][v] = p;
                psum += p;
            }
        psum += __shfl_xor(psum, 16);
        psum += __shfl_xor(psum, 32);
        lrow += psum;

        // P -> LDS as packed bf16 pairs (wave-private, XOR-swizzled u32 rows)
#pragma unroll
        for (int t = 0; t < 4; t++) {
            unsigned p0 = cvt_pk_bf16(s[t][0], s[t][1]);
            unsigned p1 = cvt_pk_bf16(s[t][2], s[t][3]);
            int idx = (t * 8 + lg * 2) ^ ((lr & 7) << 2);
            *reinterpret_cast<unsigned long long*>(&Ps[w][lr * 32 + idx]) =
                ((unsigned long long)p1 << 32) | p0;
        }

        // O += P·V : pf = P[q=lr][keys kk*32+8lg..+8] via one b128 read
#pragma unroll
        for (int kk = 0; kk < 2; kk++) {
            int ridx = (kk * 16 + lg * 4) ^ ((lr & 7) << 2);
            union { uint4 u; s16x8 v; } cvt;
            cvt.u = *reinterpret_cast<const uint4*>(&Ps[w][lr * 32 + ridx]);
            s16x8 pf = cvt.v;
#pragma unroll
            for (int t = 0; t < 4; t++) {
                int r  = t * 16 + lr;
                int cs = (kk * 4 + lg) ^ (r & 7);
                s16x8 vf = *reinterpret_cast<const s16x8*>(&Vs[cur][r * 64 + cs * 8]);
                acc[t] = __builtin_amdgcn_mfma_f32_16x16x32_bf16(pf, vf, acc[t], 0, 0, 0);
            }
        }

        __syncthreads();   // drains prefetch vmcnt; flips buffer
    }

    // epilogue: acc[t][v] = O[q = qbase+w*16+lg*4+v][d = t*16+lr]
#pragma unroll
    for (int v = 0; v < 4; v++) {
        float lq  = __shfl(lrow, (lane & 48) | (lg * 4 + v));
        float inv = 1.0f / lq;
        int q = qbase + w * 16 + lg * 4 + v;
#pragma unroll
        for (int t = 0; t < 4; t++) {
            int d = t * 16 + lr;
            Obuf[((size_t)b * NSEQ + q) * DM + h * DH + d] = f2bf(acc[t][v] * inv);
        }
    }
}

// ---------------- launch ----------------
extern "C" void kernel_launch(void* const* d_in, const int* in_sizes, int n_in,
                              void* d_out, int out_size, void* d_ws, size_t ws_size,
                              hipStream_t stream) {
    const float* q    = (const float*)d_in[0];
    const void*  mask = (const void*)d_in[1];
    const float* Wq   = (const float*)d_in[2];
    const float* Wk   = (const float*)d_in[3];
    const float* Wv   = (const float*)d_in[4];
    const float* Wo   = (const float*)d_in[5];
    const float* bo   = (const float*)d_in[6];
    float* out = (float*)d_out;

    char* ws = (char*)d_ws;
    const size_t MB = 1024 * 1024;
    unsigned short* qbf  = (unsigned short*)(ws + 0);        // 8 MB (QKV phase)
    unsigned long long* packed = (unsigned long long*)(ws + 0); // 1 MB, reuses qbf AFTER gemm_qkv
    unsigned short* Wqb  = (unsigned short*)(ws + 8  * MB);  // 2 MB
    unsigned short* Wkb  = (unsigned short*)(ws + 10 * MB);  // 2 MB
    unsigned short* Wvb  = (unsigned short*)(ws + 12 * MB);  // 2 MB
    unsigned short* Wob  = (unsigned short*)(ws + 14 * MB);  // 2 MB
    unsigned short* Qh   = (unsigned short*)(ws + 16 * MB);  // 8 MB  [B,H,N,64]
    unsigned short* Kh   = (unsigned short*)(ws + 24 * MB);  // 8 MB  [B,H,N,64]
    unsigned short* VhT  = (unsigned short*)(ws + 32 * MB);  // 8 MB  [B,H,64,N]
    unsigned short* Obuf = (unsigned short*)(ws + 40 * MB);  // 8 MB  [B,N,1024] bf16
    int*            flag = (int*)(ws + 56 * MB);             // 4 B

    hipMemsetAsync(flag, 0, 4, stream);
    mask_detect<<<1024, 256, 0, stream>>>((const unsigned int*)mask, flag);

    cvt_kernel<<<4096, 256, 0, stream>>>(q, qbf, (2 * NSEQ * DM) / 4);
    cvt4_kernel<<<dim3(1024, 4), 256, 0, stream>>>(Wq, Wk, Wv, Wo, Wqb, Wkb, Wvb, Wob);

    gemm_qkv<<<dim3(24, 32), 256, 0, stream>>>(qbf, Wqb, Wkb, Wvb, Qh, Kh, VhT);

    // qbf is dead now; pack the mask into its space (1 MB)
    mask_pack<<<1024, 256, 0, stream>>>(mask, flag, packed);

    attn_kernel<<<1024, 256, 0, stream>>>(Qh, Kh, VhT, packed, Obuf);

    gemm_out<<<dim3(8, 32), 256, 0, stream>>>(Obuf, Wob, out, bo);
}

// Round 9
// 254.396 us; speedup vs baseline: 1.3345x; 1.0161x over previous
//
#include <hip/hip_runtime.h>
#include <hip/hip_bf16.h>

typedef float fx4 __attribute__((ext_vector_type(4)));
typedef short s16x8 __attribute__((ext_vector_type(8)));

#define NSEQ 2048
#define DM   1024
#define NH   16
#define DH   64
#define MROWS 4096               // B * NSEQ
#define NWORDS (2 * NSEQ * (NSEQ / 64))   // 131072 packed-mask words

// QK scale with log2(e) folded in: softmax runs in exp2 domain.
#define QK_SCALE (0.125f * 1.44269504088896f)

__device__ __forceinline__ unsigned short f2bf(float f) {
    union { float f; unsigned u; } c; c.f = f;
    unsigned u = c.u;
    unsigned r = u + 0x7FFFu + ((u >> 16) & 1u);   // round-to-nearest-even
    return (unsigned short)(r >> 16);
}

__device__ __forceinline__ float exp2_fast(float x) {
#if __has_builtin(__builtin_amdgcn_exp2f)
    return __builtin_amdgcn_exp2f(x);
#else
    return exp2f(x);
#endif
}

// hardware packed f32->bf16 (RNE): dst.lo = bf16(a), dst.hi = bf16(b)
__device__ __forceinline__ unsigned cvt_pk_bf16(float a, float b) {
    unsigned r;
    asm("v_cvt_pk_bf16_f32 %0, %1, %2" : "=v"(r) : "v"(a), "v"(b));
    return r;
}

__device__ __forceinline__ fx4 zero4() {
    fx4 z; z[0] = 0.f; z[1] = 0.f; z[2] = 0.f; z[3] = 0.f; return z;
}

// async global->LDS, 16B per lane. LDS dest = wave-uniform base + lane*16.
__device__ __forceinline__ void gload16(const void* g, void* l) {
    __builtin_amdgcn_global_load_lds(
        (const __attribute__((address_space(1))) unsigned int*)g,
        (__attribute__((address_space(3))) unsigned int*)l,
        16, 0, 0);
}

// ---------------- fp32 -> bf16 conversion ----------------
__global__ void cvt_kernel(const float* __restrict__ in,
                           unsigned short* __restrict__ out, int n4) {
    int i = blockIdx.x * blockDim.x + threadIdx.x;
    if (i >= n4) return;
    float4 v = reinterpret_cast<const float4*>(in)[i];
    ushort4 o;
    o.x = f2bf(v.x); o.y = f2bf(v.y); o.z = f2bf(v.z); o.w = f2bf(v.w);
    reinterpret_cast<ushort4*>(out)[i] = o;
}

// 4 weight matrices in one launch; grid MUST be (1024, 4): DM*DM/4/256 = 1024.
__global__ void cvt4_kernel(const float* __restrict__ w0, const float* __restrict__ w1,
                            const float* __restrict__ w2, const float* __restrict__ w3,
                            unsigned short* __restrict__ o0, unsigned short* __restrict__ o1,
                            unsigned short* __restrict__ o2, unsigned short* __restrict__ o3) {
    const float* in; unsigned short* out;
    switch (blockIdx.y) {
        case 0:  in = w0; out = o0; break;
        case 1:  in = w1; out = o1; break;
        case 2:  in = w2; out = o2; break;
        default: in = w3; out = o3; break;
    }
    int i = blockIdx.x * blockDim.x + threadIdx.x;
    float4 v = reinterpret_cast<const float4*>(in)[i];
    ushort4 o;
    o.x = f2bf(v.x); o.y = f2bf(v.y); o.z = f2bf(v.z); o.w = f2bf(v.w);
    reinterpret_cast<ushort4*>(out)[i] = o;
}

// ---------------- mask dtype detection ----------------
// int32 0/1 data can never make a u32 word > 1; packed bool bytes will.
__global__ void mask_detect(const unsigned int* __restrict__ m, int* __restrict__ flag) {
    unsigned mx = 0;
    int stride = gridDim.x * blockDim.x;
    for (int i = blockIdx.x * blockDim.x + threadIdx.x; i < (2 * NSEQ * NSEQ) / 4; i += stride) {
        unsigned v = m[i];
        mx = v > mx ? v : mx;
    }
    if (__any(mx > 1u)) {
        if ((threadIdx.x & 63) == 0) atomicOr(flag, 1);
    }
}

// ---------------- mask bit-pack ----------------
// packed[w] covers keys kw*64..+63 of global row bq (w = bq*32 + kw).
// Bit p <-> key ((p>>2)&3)*16 + ((p>>4)&3)*4 + (p&3): attn lane (lg,lr)
// finds its 16 bits (keys t*16+lg*4+v) contiguously at p = lg*16 + t*4 + v.
__global__ void mask_pack(const void* __restrict__ mask, const int* __restrict__ mflag,
                          unsigned long long* __restrict__ packed) {
    const int flg  = mflag[0];
    const int lane = threadIdx.x & 63;
    const int wpb  = blockDim.x >> 6;
    const int perm = ((lane >> 2) & 3) * 16 + ((lane >> 4) & 3) * 4 + (lane & 3);
    size_t w = (size_t)blockIdx.x * wpb + (threadIdx.x >> 6);
    const size_t stride = (size_t)gridDim.x * wpb;
    for (; w < NWORDS; w += stride) {
        size_t elem = (w >> 5) * (size_t)NSEQ + (size_t)(w & 31) * 64 + perm;
        int mv = flg ? (int)((const unsigned char*)mask)[elem]
                     : ((const int*)mask)[elem];
        unsigned long long bits = __ballot(mv != 0);
        if (lane == 0) packed[w] = bits;
    }
}

// ---------------- fused QKV GEMM (m97 staging; UNCHANGED from round 8) --------
__global__ __launch_bounds__(256) void gemm_qkv(
        const unsigned short* __restrict__ A,
        const unsigned short* __restrict__ Wq,
        const unsigned short* __restrict__ Wk,
        const unsigned short* __restrict__ Wv,
        unsigned short* __restrict__ Qh,     // [B,H,N,64], pre-scaled by QK_SCALE
        unsigned short* __restrict__ Kh,     // [B,H,N,64]
        unsigned short* __restrict__ VhT) {  // [B,H,64,N]
    __shared__ unsigned short As[128 * 32];
    __shared__ unsigned short Bs[128 * 32];

    const int tid  = threadIdx.x;
    const int lane = tid & 63;
    const int w    = tid >> 6;
    const int lr   = lane & 15;
    const int lg   = lane >> 4;
    const int wr   = (w >> 1) * 64;
    const int wc   = (w & 1) * 64;
    const int rowbase = blockIdx.y * 128;
    const int seg     = blockIdx.x >> 3;              // 0,1,2
    const int cb      = (blockIdx.x & 7) * 128;
    const unsigned short* W = seg == 0 ? Wq : (seg == 1 ? Wk : Wv);
    const float scale = seg == 0 ? QK_SCALE : 1.0f;

    fx4 acc[4][4];
#pragma unroll
    for (int i = 0; i < 4; i++)
#pragma unroll
        for (int j = 0; j < 4; j++) acc[i][j] = zero4();

    for (int k0 = 0; k0 < DM; k0 += 32) {
        __syncthreads();
#pragma unroll
        for (int i = 0; i < 2; i++) {
            int j = i * 256 + w * 64 + lane;
            int r = j >> 2, c8 = (j & 3) * 8;
            gload16(A + (size_t)(rowbase + r) * DM + k0 + c8,
                    As + (size_t)(i * 256 + w * 64) * 8);
            gload16(W + (size_t)(cb + r) * DM + k0 + c8,
                    Bs + (size_t)(i * 256 + w * 64) * 8);
        }
        __syncthreads();

        s16x8 af[4], bf[4];
#pragma unroll
        for (int mi = 0; mi < 4; mi++)
            af[mi] = *reinterpret_cast<const s16x8*>(&As[(wr + mi * 16 + lr) * 32 + 8 * lg]);
#pragma unroll
        for (int ni = 0; ni < 4; ni++)
            bf[ni] = *reinterpret_cast<const s16x8*>(&Bs[(wc + ni * 16 + lr) * 32 + 8 * lg]);
#pragma unroll
        for (int mi = 0; mi < 4; mi++)
#pragma unroll
            for (int ni = 0; ni < 4; ni++)
                acc[mi][ni] = __builtin_amdgcn_mfma_f32_16x16x32_bf16(af[mi], bf[ni], acc[mi][ni], 0, 0, 0);
    }

#pragma unroll
    for (int mi = 0; mi < 4; mi++) {
#pragma unroll
        for (int ni = 0; ni < 4; ni++) {
#pragma unroll
            for (int v = 0; v < 4; v++) {
                int m    = rowbase + wr + mi * 16 + lg * 4 + v;
                int cseg = cb + wc + ni * 16 + lr;
                float val = acc[mi][ni][v] * scale;
                int b = m >> 11, nseq = m & 2047;
                int h = cseg >> 6, dh = cseg & 63;
                if (seg < 2) {
                    unsigned short* dst = seg == 0 ? Qh : Kh;
                    dst[((size_t)(b * NH + h) * NSEQ + nseq) * DH + dh] = f2bf(val);
                } else {
                    VhT[((size_t)(b * NH + h) * DH + dh) * NSEQ + nseq] = f2bf(val);
                }
            }
        }
    }
}

// ---------------- output GEMM: 64x128 tile, 2 blocks/CU ----------------
// grid (8, 64); 4 waves 2x2, each 32x64 (acc 2x4). Same (m,c)->memory map.
__global__ __launch_bounds__(256) void gemm_out(
        const unsigned short* __restrict__ A,    // Obuf bf16 [4096][1024]
        const unsigned short* __restrict__ W,
        float* __restrict__ out,
        const float* __restrict__ bias) {
    __shared__ unsigned short As[64 * 32];
    __shared__ unsigned short Bs[128 * 32];

    const int tid  = threadIdx.x;
    const int lane = tid & 63;
    const int w    = tid >> 6;
    const int lr   = lane & 15;
    const int lg   = lane >> 4;
    const int wr   = (w >> 1) * 32;          // wave rows: 0 / 32
    const int wc   = (w & 1) * 64;           // wave cols: 0 / 64
    const int rowbase = blockIdx.y * 64;
    const int colbase = blockIdx.x * 128;

    fx4 acc[2][4];
#pragma unroll
    for (int i = 0; i < 2; i++)
#pragma unroll
        for (int j = 0; j < 4; j++) acc[i][j] = zero4();

    for (int k0 = 0; k0 < DM; k0 += 32) {
        __syncthreads();
        {
            // A: 64x32 = 256 chunks (16B); chunk j -> row j>>2, shorts (j&3)*8
            int j = tid;
            int r = j >> 2, c8 = (j & 3) * 8;
            gload16(A + (size_t)(rowbase + r) * DM + k0 + c8,
                    As + (size_t)(w * 64) * 8);
            // B: 128x32 = 512 chunks; first 256 via j, last 256 via j+256
            gload16(W + (size_t)(colbase + r) * DM + k0 + c8,
                    Bs + (size_t)(w * 64) * 8);
            int r2 = 64 + (j >> 2);
            gload16(W + (size_t)(colbase + r2) * DM + k0 + c8,
                    Bs + (size_t)(256 + w * 64) * 8);
        }
        __syncthreads();

        s16x8 af[2], bf[4];
#pragma unroll
        for (int mi = 0; mi < 2; mi++)
            af[mi] = *reinterpret_cast<const s16x8*>(&As[(wr + mi * 16 + lr) * 32 + 8 * lg]);
#pragma unroll
        for (int ni = 0; ni < 4; ni++)
            bf[ni] = *reinterpret_cast<const s16x8*>(&Bs[(wc + ni * 16 + lr) * 32 + 8 * lg]);
#pragma unroll
        for (int mi = 0; mi < 2; mi++)
#pragma unroll
            for (int ni = 0; ni < 4; ni++)
                acc[mi][ni] = __builtin_amdgcn_mfma_f32_16x16x32_bf16(af[mi], bf[ni], acc[mi][ni], 0, 0, 0);
    }

#pragma unroll
    for (int mi = 0; mi < 2; mi++)
#pragma unroll
        for (int ni = 0; ni < 4; ni++)
#pragma unroll
            for (int v = 0; v < 4; v++) {
                int m = rowbase + wr + mi * 16 + lg * 4 + v;
                int c = colbase + wc + ni * 16 + lr;
                out[(size_t)m * DM + c] = acc[mi][ni][v] + bias[c];
            }
}

// ---------------- flash attention (swapped QK^T, in-register softmax) --------
// 1024 blocks (XCD-swizzled), 4 waves; wave w owns q rows w*16..+15.
// Swapped MFMA: s[t][v] = S[q = w*16+lr][key = t*16+lg*4+v] -> softmax per-lane.
__global__ __launch_bounds__(256) void attn_kernel(
        const unsigned short* __restrict__ Qh,   // [B,H,N,64] bf16 (scaled by QK_SCALE)
        const unsigned short* __restrict__ Kh,   // [B,H,N,64] bf16
        const unsigned short* __restrict__ VhT,  // [B,H,64,N] bf16
        const unsigned long long* __restrict__ Mp, // packed mask [B*N][32]
        unsigned short* __restrict__ Obuf) {     // [B,N,1024] bf16
    __shared__ unsigned short Ks[2][64 * 64];    // XOR-swizzled rows, double-buffered
    __shared__ unsigned short Vs[2][64 * 64];    // V^T rows (row=d), swizzled, dbuf
    __shared__ __align__(16) unsigned int Ps[4][16 * 32]; // P bf16-pairs, XOR-swz

    const int tid  = threadIdx.x;
    const int lane = tid & 63;
    const int w    = tid >> 6;
    const int lr   = lane & 15;
    const int lg   = lane >> 4;

    // bijective XCD swizzle: 1024 = 8 XCDs x 128 contiguous blocks
    const int wg    = ((blockIdx.x & 7) << 7) + (blockIdx.x >> 3);
    const int qbase = (wg & 31) << 6;            // 32 q-tiles of 64
    const int bh    = wg >> 5;                   // 0..31
    const int b     = bh >> 4;
    const int h     = bh & 15;

    // Q fragment (B-operand): lane holds Q[q = w*16+lr][k = kk*32+8lg..+8]
    s16x8 qf[2];
    const size_t qrow = (size_t)bh * NSEQ + qbase + w * 16 + lr;
#pragma unroll
    for (int kk = 0; kk < 2; kk++)
        qf[kk] = *reinterpret_cast<const s16x8*>(Qh + qrow * DH + kk * 32 + 8 * lg);

    float mreg = -3.0e38f, lrow = 0.f;
    fx4 acc[4];
#pragma unroll
    for (int t = 0; t < 4; t++) acc[t] = zero4();

    const size_t mbase = ((size_t)b * NSEQ + qbase + w * 16 + lr) * (NSEQ / 64);

    // stage tile kv into buffer d: linear LDS dest + inverse-swizzled source
    auto stage = [&](int d, int kv0) {
#pragma unroll
        for (int i = 0; i < 2; i++) {
            int u  = i * 256 + w * 64 + lane;    // dest chunk 0..511
            int r  = u >> 3, cs = u & 7;
            int cu = cs ^ (r & 7);
            gload16(Kh + ((size_t)bh * NSEQ + kv0 + r) * DH + cu * 8,
                    &Ks[d][(size_t)(i * 256 + w * 64) * 8]);
            gload16(VhT + ((size_t)bh * DH + r) * NSEQ + kv0 + cu * 8,
                    &Vs[d][(size_t)(i * 256 + w * 64) * 8]);
        }
    };

    stage(0, 0);
    __syncthreads();

    for (int it = 0; it < NSEQ / 64; it++) {
        const int cur = it & 1;
        if (it < NSEQ / 64 - 1) stage(cur ^ 1, (it + 1) << 6);   // prefetch next

        // this lane's 16 mask bits (its q-row, keys t*16+lg*4+v at bit t*4+v)
        unsigned long long pwm = Mp[mbase + it];
        unsigned mb = (unsigned)((pwm >> (lg * 16)) & 0xFFFFull);

        // S^T = K · Q^T : 8 MFMAs
        fx4 s[4];
        __builtin_amdgcn_s_setprio(1);
#pragma unroll
        for (int t = 0; t < 4; t++) {
            s[t] = zero4();
#pragma unroll
            for (int kk = 0; kk < 2; kk++) {
                int r  = t * 16 + lr;
                int cs = (kk * 4 + lg) ^ (r & 7);
                s16x8 kf = *reinterpret_cast<const s16x8*>(&Ks[cur][r * 64 + cs * 8]);
                s[t] = __builtin_amdgcn_mfma_f32_16x16x32_bf16(kf, qf[kk], s[t], 0, 0, 0);
            }
        }
        __builtin_amdgcn_s_setprio(0);

        // mask + in-register max over this lane's 16 keys
        float tmax = -3.0e38f;
#pragma unroll
        for (int t = 0; t < 4; t++)
#pragma unroll
            for (int v = 0; v < 4; v++) {
                float sv = (mb & (1u << (t * 4 + v))) ? -3.0e38f : s[t][v];
                s[t][v] = sv;
                tmax = fmaxf(tmax, sv);
            }
        tmax = fmaxf(tmax, __shfl_xor(tmax, 16));
        tmax = fmaxf(tmax, __shfl_xor(tmax, 32));

        // defer-max: rescale only when the row max grows by > 8 (exp2 domain)
        if (__any(tmax > mreg + 8.0f)) {
            float mn = fmaxf(mreg, tmax);
            float sc = exp2_fast(mreg - mn);
            mreg = mn;
            lrow *= sc;
#pragma unroll
            for (int v = 0; v < 4; v++) {
                float scv = __shfl(sc, (lane & 48) | (lg * 4 + v));
#pragma unroll
                for (int t = 0; t < 4; t++) acc[t][v] *= scv;
            }
        }

        // exp2 + row sum (in-register + 2 shfl)
        float psum = 0.f;
#pragma unroll
        for (int t = 0; t < 4; t++)
#pragma unroll
            for (int v = 0; v < 4; v++) {
                float p = exp2_fast(s[t][v] - mreg);
                s[t][v] = p;
                psum += p;
            }
        psum += __shfl_xor(psum, 16);
        psum += __shfl_xor(psum, 32);
        lrow += psum;

        // P -> LDS as packed bf16 pairs (wave-private, XOR-swizzled u32 rows)
#pragma unroll
        for (int t = 0; t < 4; t++) {
            unsigned p0 = cvt_pk_bf16(s[t][0], s[t][1]);
            unsigned p1 = cvt_pk_bf16(s[t][2], s[t][3]);
            int idx = (t * 8 + lg * 2) ^ ((lr & 7) << 2);
            *reinterpret_cast<unsigned long long*>(&Ps[w][lr * 32 + idx]) =
                ((unsigned long long)p1 << 32) | p0;
        }

        // O += P·V : pf = P[q=lr][keys kk*32+8lg..+8] via one b128 read
        __builtin_amdgcn_s_setprio(1);
#pragma unroll
        for (int kk = 0; kk < 2; kk++) {
            int ridx = (kk * 16 + lg * 4) ^ ((lr & 7) << 2);
            union { uint4 u; s16x8 v; } cvt;
            cvt.u = *reinterpret_cast<const uint4*>(&Ps[w][lr * 32 + ridx]);
            s16x8 pf = cvt.v;
#pragma unroll
            for (int t = 0; t < 4; t++) {
                int r  = t * 16 + lr;
                int cs = (kk * 4 + lg) ^ (r & 7);
                s16x8 vf = *reinterpret_cast<const s16x8*>(&Vs[cur][r * 64 + cs * 8]);
                acc[t] = __builtin_amdgcn_mfma_f32_16x16x32_bf16(pf, vf, acc[t], 0, 0, 0);
            }
        }
        __builtin_amdgcn_s_setprio(0);

        __syncthreads();   // drains prefetch vmcnt; flips buffer
    }

    // epilogue: acc[t][v] = O[q = qbase+w*16+lg*4+v][d = t*16+lr]
#pragma unroll
    for (int v = 0; v < 4; v++) {
        float lq  = __shfl(lrow, (lane & 48) | (lg * 4 + v));
        float inv = 1.0f / lq;
        int q = qbase + w * 16 + lg * 4 + v;
#pragma unroll
        for (int t = 0; t < 4; t++) {
            int d = t * 16 + lr;
            Obuf[((size_t)b * NSEQ + q) * DM + h * DH + d] = f2bf(acc[t][v] * inv);
        }
    }
}

// ---------------- launch ----------------
extern "C" void kernel_launch(void* const* d_in, const int* in_sizes, int n_in,
                              void* d_out, int out_size, void* d_ws, size_t ws_size,
                              hipStream_t stream) {
    const float* q    = (const float*)d_in[0];
    const void*  mask = (const void*)d_in[1];
    const float* Wq   = (const float*)d_in[2];
    const float* Wk   = (const float*)d_in[3];
    const float* Wv   = (const float*)d_in[4];
    const float* Wo   = (const float*)d_in[5];
    const float* bo   = (const float*)d_in[6];
    float* out = (float*)d_out;

    char* ws = (char*)d_ws;
    const size_t MB = 1024 * 1024;
    unsigned short* qbf  = (unsigned short*)(ws + 0);        // 8 MB (QKV phase)
    unsigned long long* packed = (unsigned long long*)(ws + 0); // 1 MB, reuses qbf AFTER gemm_qkv
    unsigned short* Wqb  = (unsigned short*)(ws + 8  * MB);  // 2 MB
    unsigned short* Wkb  = (unsigned short*)(ws + 10 * MB);  // 2 MB
    unsigned short* Wvb  = (unsigned short*)(ws + 12 * MB);  // 2 MB
    unsigned short* Wob  = (unsigned short*)(ws + 14 * MB);  // 2 MB
    unsigned short* Qh   = (unsigned short*)(ws + 16 * MB);  // 8 MB  [B,H,N,64]
    unsigned short* Kh   = (unsigned short*)(ws + 24 * MB);  // 8 MB  [B,H,N,64]
    unsigned short* VhT  = (unsigned short*)(ws + 32 * MB);  // 8 MB  [B,H,64,N]
    unsigned short* Obuf = (unsigned short*)(ws + 40 * MB);  // 8 MB  [B,N,1024] bf16
    int*            flag = (int*)(ws + 56 * MB);             // 4 B

    hipMemsetAsync(flag, 0, 4, stream);
    mask_detect<<<1024, 256, 0, stream>>>((const unsigned int*)mask, flag);

    cvt_kernel<<<4096, 256, 0, stream>>>(q, qbf, (2 * NSEQ * DM) / 4);
    cvt4_kernel<<<dim3(1024, 4), 256, 0, stream>>>(Wq, Wk, Wv, Wo, Wqb, Wkb, Wvb, Wob);

    gemm_qkv<<<dim3(24, 32), 256, 0, stream>>>(qbf, Wqb, Wkb, Wvb, Qh, Kh, VhT);

    // qbf is dead now; pack the mask into its space (1 MB)
    mask_pack<<<1024, 256, 0, stream>>>(mask, flag, packed);

    attn_kernel<<<1024, 256, 0, stream>>>(Qh, Kh, VhT, packed, Obuf);

    gemm_out<<<dim3(8, 64), 256, 0, stream>>>(Obuf, Wob, out, bo);
}

// Round 10
// 253.898 us; speedup vs baseline: 1.3371x; 1.0020x over previous
//
#include <hip/hip_runtime.h>
#include <hip/hip_bf16.h>

typedef float fx4  __attribute__((ext_vector_type(4)));
typedef float fx16 __attribute__((ext_vector_type(16)));
typedef short s16x8 __attribute__((ext_vector_type(8)));

#define NSEQ 2048
#define DM   1024
#define NH   16
#define DH   64
#define MROWS 4096               // B * NSEQ
#define NWORDS (2 * NSEQ * (NSEQ / 64))   // 131072 packed-mask words

// QK scale with log2(e) folded in: softmax runs in exp2 domain.
#define QK_SCALE (0.125f * 1.44269504088896f)

__device__ __forceinline__ unsigned short f2bf(float f) {
    union { float f; unsigned u; } c; c.f = f;
    unsigned u = c.u;
    unsigned r = u + 0x7FFFu + ((u >> 16) & 1u);   // round-to-nearest-even
    return (unsigned short)(r >> 16);
}

__device__ __forceinline__ float exp2_fast(float x) {
#if __has_builtin(__builtin_amdgcn_exp2f)
    return __builtin_amdgcn_exp2f(x);
#else
    return exp2f(x);
#endif
}

// hardware packed f32->bf16 (RNE): dst.lo = bf16(a), dst.hi = bf16(b)
__device__ __forceinline__ unsigned cvt_pk_bf16(float a, float b) {
    unsigned r;
    asm("v_cvt_pk_bf16_f32 %0, %1, %2" : "=v"(r) : "v"(a), "v"(b));
    return r;
}

__device__ __forceinline__ fx4 zero4() {
    fx4 z; z[0] = 0.f; z[1] = 0.f; z[2] = 0.f; z[3] = 0.f; return z;
}

__device__ __forceinline__ fx16 zero16() {
    fx16 z;
#pragma unroll
    for (int i = 0; i < 16; i++) z[i] = 0.f;
    return z;
}

// async global->LDS, 16B per lane. LDS dest = wave-uniform base + lane*16.
__device__ __forceinline__ void gload16(const void* g, void* l) {
    __builtin_amdgcn_global_load_lds(
        (const __attribute__((address_space(1))) unsigned int*)g,
        (__attribute__((address_space(3))) unsigned int*)l,
        16, 0, 0);
}

// ---------------- fp32 -> bf16 conversion ----------------
__global__ void cvt_kernel(const float* __restrict__ in,
                           unsigned short* __restrict__ out, int n4) {
    int i = blockIdx.x * blockDim.x + threadIdx.x;
    if (i >= n4) return;
    float4 v = reinterpret_cast<const float4*>(in)[i];
    ushort4 o;
    o.x = f2bf(v.x); o.y = f2bf(v.y); o.z = f2bf(v.z); o.w = f2bf(v.w);
    reinterpret_cast<ushort4*>(out)[i] = o;
}

// 4 weight matrices in one launch; grid MUST be (1024, 4): DM*DM/4/256 = 1024.
__global__ void cvt4_kernel(const float* __restrict__ w0, const float* __restrict__ w1,
                            const float* __restrict__ w2, const float* __restrict__ w3,
                            unsigned short* __restrict__ o0, unsigned short* __restrict__ o1,
                            unsigned short* __restrict__ o2, unsigned short* __restrict__ o3) {
    const float* in; unsigned short* out;
    switch (blockIdx.y) {
        case 0:  in = w0; out = o0; break;
        case 1:  in = w1; out = o1; break;
        case 2:  in = w2; out = o2; break;
        default: in = w3; out = o3; break;
    }
    int i = blockIdx.x * blockDim.x + threadIdx.x;
    float4 v = reinterpret_cast<const float4*>(in)[i];
    ushort4 o;
    o.x = f2bf(v.x); o.y = f2bf(v.y); o.z = f2bf(v.z); o.w = f2bf(v.w);
    reinterpret_cast<ushort4*>(out)[i] = o;
}

// ---------------- mask dtype detection ----------------
// int32 0/1 data can never make a u32 word > 1; packed bool bytes will.
__global__ void mask_detect(const unsigned int* __restrict__ m, int* __restrict__ flag) {
    unsigned mx = 0;
    int stride = gridDim.x * blockDim.x;
    for (int i = blockIdx.x * blockDim.x + threadIdx.x; i < (2 * NSEQ * NSEQ) / 4; i += stride) {
        unsigned v = m[i];
        mx = v > mx ? v : mx;
    }
    if (__any(mx > 1u)) {
        if ((threadIdx.x & 63) == 0) atomicOr(flag, 1);
    }
}

// ---------------- mask bit-pack (32x32 layout) ----------------
// packed[w] covers keys kw*64..+63 of global row bq (w = bq*32 + kw).
// Bit p <-> key (p&3) + 8*((p>>2)&3) + 4*(p>>5) + 32*((p>>4)&1):
// attn lane (hi = lane>>5) extracts u32 = pw >> (32*hi); bit (16*kh + reg)
// corresponds to S^T reg `reg` of key-half kh.
__global__ void mask_pack(const void* __restrict__ mask, const int* __restrict__ mflag,
                          unsigned long long* __restrict__ packed) {
    const int flg  = mflag[0];
    const int lane = threadIdx.x & 63;
    const int wpb  = blockDim.x >> 6;
    const int perm = (lane & 3) + 8 * ((lane >> 2) & 3) + 4 * (lane >> 5) + 32 * ((lane >> 4) & 1);
    size_t w = (size_t)blockIdx.x * wpb + (threadIdx.x >> 6);
    const size_t stride = (size_t)gridDim.x * wpb;
    for (; w < NWORDS; w += stride) {
        size_t elem = (w >> 5) * (size_t)NSEQ + (size_t)(w & 31) * 64 + perm;
        int mv = flg ? (int)((const unsigned char*)mask)[elem]
                     : ((const int*)mask)[elem];
        unsigned long long bits = __ballot(mv != 0);
        if (lane == 0) packed[w] = bits;
    }
}

// ---------------- fused QKV GEMM (m97 staging; UNCHANGED) ----------------
__global__ __launch_bounds__(256) void gemm_qkv(
        const unsigned short* __restrict__ A,
        const unsigned short* __restrict__ Wq,
        const unsigned short* __restrict__ Wk,
        const unsigned short* __restrict__ Wv,
        unsigned short* __restrict__ Qh,     // [B,H,N,64], pre-scaled by QK_SCALE
        unsigned short* __restrict__ Kh,     // [B,H,N,64]
        unsigned short* __restrict__ VhT) {  // [B,H,64,N]
    __shared__ unsigned short As[128 * 32];
    __shared__ unsigned short Bs[128 * 32];

    const int tid  = threadIdx.x;
    const int lane = tid & 63;
    const int w    = tid >> 6;
    const int lr   = lane & 15;
    const int lg   = lane >> 4;
    const int wr   = (w >> 1) * 64;
    const int wc   = (w & 1) * 64;
    const int rowbase = blockIdx.y * 128;
    const int seg     = blockIdx.x >> 3;              // 0,1,2
    const int cb      = (blockIdx.x & 7) * 128;
    const unsigned short* W = seg == 0 ? Wq : (seg == 1 ? Wk : Wv);
    const float scale = seg == 0 ? QK_SCALE : 1.0f;

    fx4 acc[4][4];
#pragma unroll
    for (int i = 0; i < 4; i++)
#pragma unroll
        for (int j = 0; j < 4; j++) acc[i][j] = zero4();

    for (int k0 = 0; k0 < DM; k0 += 32) {
        __syncthreads();
#pragma unroll
        for (int i = 0; i < 2; i++) {
            int j = i * 256 + w * 64 + lane;
            int r = j >> 2, c8 = (j & 3) * 8;
            gload16(A + (size_t)(rowbase + r) * DM + k0 + c8,
                    As + (size_t)(i * 256 + w * 64) * 8);
            gload16(W + (size_t)(cb + r) * DM + k0 + c8,
                    Bs + (size_t)(i * 256 + w * 64) * 8);
        }
        __syncthreads();

        s16x8 af[4], bf[4];
#pragma unroll
        for (int mi = 0; mi < 4; mi++)
            af[mi] = *reinterpret_cast<const s16x8*>(&As[(wr + mi * 16 + lr) * 32 + 8 * lg]);
#pragma unroll
        for (int ni = 0; ni < 4; ni++)
            bf[ni] = *reinterpret_cast<const s16x8*>(&Bs[(wc + ni * 16 + lr) * 32 + 8 * lg]);
#pragma unroll
        for (int mi = 0; mi < 4; mi++)
#pragma unroll
            for (int ni = 0; ni < 4; ni++)
                acc[mi][ni] = __builtin_amdgcn_mfma_f32_16x16x32_bf16(af[mi], bf[ni], acc[mi][ni], 0, 0, 0);
    }

#pragma unroll
    for (int mi = 0; mi < 4; mi++) {
#pragma unroll
        for (int ni = 0; ni < 4; ni++) {
#pragma unroll
            for (int v = 0; v < 4; v++) {
                int m    = rowbase + wr + mi * 16 + lg * 4 + v;
                int cseg = cb + wc + ni * 16 + lr;
                float val = acc[mi][ni][v] * scale;
                int b = m >> 11, nseq = m & 2047;
                int h = cseg >> 6, dh = cseg & 63;
                if (seg < 2) {
                    unsigned short* dst = seg == 0 ? Qh : Kh;
                    dst[((size_t)(b * NH + h) * NSEQ + nseq) * DH + dh] = f2bf(val);
                } else {
                    VhT[((size_t)(b * NH + h) * DH + dh) * NSEQ + nseq] = f2bf(val);
                }
            }
        }
    }
}

// ---------------- output GEMM: 64x128 tile (UNCHANGED) ----------------
__global__ __launch_bounds__(256) void gemm_out(
        const unsigned short* __restrict__ A,    // Obuf bf16 [4096][1024]
        const unsigned short* __restrict__ W,
        float* __restrict__ out,
        const float* __restrict__ bias) {
    __shared__ unsigned short As[64 * 32];
    __shared__ unsigned short Bs[128 * 32];

    const int tid  = threadIdx.x;
    const int lane = tid & 63;
    const int w    = tid >> 6;
    const int lr   = lane & 15;
    const int lg   = lane >> 4;
    const int wr   = (w >> 1) * 32;          // wave rows: 0 / 32
    const int wc   = (w & 1) * 64;           // wave cols: 0 / 64
    const int rowbase = blockIdx.y * 64;
    const int colbase = blockIdx.x * 128;

    fx4 acc[2][4];
#pragma unroll
    for (int i = 0; i < 2; i++)
#pragma unroll
        for (int j = 0; j < 4; j++) acc[i][j] = zero4();

    for (int k0 = 0; k0 < DM; k0 += 32) {
        __syncthreads();
        {
            int j = tid;
            int r = j >> 2, c8 = (j & 3) * 8;
            gload16(A + (size_t)(rowbase + r) * DM + k0 + c8,
                    As + (size_t)(w * 64) * 8);
            gload16(W + (size_t)(colbase + r) * DM + k0 + c8,
                    Bs + (size_t)(w * 64) * 8);
            int r2 = 64 + (j >> 2);
            gload16(W + (size_t)(colbase + r2) * DM + k0 + c8,
                    Bs + (size_t)(256 + w * 64) * 8);
        }
        __syncthreads();

        s16x8 af[2], bf[4];
#pragma unroll
        for (int mi = 0; mi < 2; mi++)
            af[mi] = *reinterpret_cast<const s16x8*>(&As[(wr + mi * 16 + lr) * 32 + 8 * lg]);
#pragma unroll
        for (int ni = 0; ni < 4; ni++)
            bf[ni] = *reinterpret_cast<const s16x8*>(&Bs[(wc + ni * 16 + lr) * 32 + 8 * lg]);
#pragma unroll
        for (int mi = 0; mi < 2; mi++)
#pragma unroll
            for (int ni = 0; ni < 4; ni++)
                acc[mi][ni] = __builtin_amdgcn_mfma_f32_16x16x32_bf16(af[mi], bf[ni], acc[mi][ni], 0, 0, 0);
    }

#pragma unroll
    for (int mi = 0; mi < 2; mi++)
#pragma unroll
        for (int ni = 0; ni < 4; ni++)
#pragma unroll
            for (int v = 0; v < 4; v++) {
                int m = rowbase + wr + mi * 16 + lg * 4 + v;
                int c = colbase + wc + ni * 16 + lr;
                out[(size_t)m * DM + c] = acc[mi][ni][v] + bias[c];
            }
}

// ---------------- flash attention: 32x32 MFMA, P fully in registers ---------
// grid 512 (XCD-swizzled 8x64), 4 waves; wave w owns q rows w*32..+31.
// Swapped: S^T = mfma_32x32x16(K, Q): lane holds S^T[key-rows][q = lane&31];
// key rows (per key-half kh): (reg&3) + 8*(reg>>2) + 4*hi + 32*kh.
__global__ __launch_bounds__(256) void attn_kernel(
        const unsigned short* __restrict__ Qh,   // [B,H,N,64] bf16 (scaled by QK_SCALE)
        const unsigned short* __restrict__ Kh,   // [B,H,N,64] bf16
        const unsigned short* __restrict__ VhT,  // [B,H,64,N] bf16
        const unsigned long long* __restrict__ Mp, // packed mask [B*N][32]
        unsigned short* __restrict__ Obuf) {     // [B,N,1024] bf16
    __shared__ unsigned short Ks[2][64 * 64];    // XOR-swizzled rows, double-buffered
    __shared__ unsigned short Vs[2][64 * 64];    // V^T rows (row=d), swizzled, dbuf

    const int tid  = threadIdx.x;
    const int lane = tid & 63;
    const int w    = tid >> 6;
    const int l31  = lane & 31;
    const int hi   = lane >> 5;

    // bijective XCD swizzle: 512 = 8 XCDs x 64 contiguous blocks
    const int wg    = ((blockIdx.x & 7) << 6) | (blockIdx.x >> 3);
    const int qbase = (wg & 15) << 7;            // 16 q-tiles of 128
    const int bh    = wg >> 4;                   // 0..31
    const int b     = bh >> 4;
    const int h     = bh & 15;

    // Q fragment (B-operand of 32x32x16): lane holds Q[q = w*32+l31][dh = s*16+hi*8+j]
    s16x8 qf[4];
    const size_t qrow = (size_t)bh * NSEQ + qbase + w * 32 + l31;
#pragma unroll
    for (int s = 0; s < 4; s++)
        qf[s] = *reinterpret_cast<const s16x8*>(Qh + qrow * DH + s * 16 + hi * 8);

    float mreg = -3.0e38f, lrow = 0.f;
    fx16 po[2];
    po[0] = zero16(); po[1] = zero16();

    const size_t mbase = ((size_t)b * NSEQ + qbase + w * 32 + l31) * (NSEQ / 64);

    // stage tile kv into buffer d: linear LDS dest + inverse-swizzled source
    auto stage = [&](int d, int kv0) {
#pragma unroll
        for (int i = 0; i < 2; i++) {
            int u  = i * 256 + w * 64 + lane;    // dest chunk 0..511
            int r  = u >> 3, cs = u & 7;
            int cu = cs ^ (r & 7);
            gload16(Kh + ((size_t)bh * NSEQ + kv0 + r) * DH + cu * 8,
                    &Ks[d][(size_t)(i * 256 + w * 64) * 8]);
            gload16(VhT + ((size_t)bh * DH + r) * NSEQ + kv0 + cu * 8,
                    &Vs[d][(size_t)(i * 256 + w * 64) * 8]);
        }
    };

    stage(0, 0);
    __syncthreads();

    for (int it = 0; it < NSEQ / 64; it++) {
        const int cur = it & 1;
        if (it < NSEQ / 64 - 1) stage(cur ^ 1, (it + 1) << 6);   // prefetch next

        // this lane's 32 mask bits: u32 half of the q-row's packed word
        unsigned long long pwm = Mp[mbase + it];
        unsigned m32 = (unsigned)(pwm >> (hi * 32));

        // S^T = K · Q^T : 8 MFMAs of 32x32x16 (2 key-halves x 4 dh-steps)
        fx16 sx[2];
        __builtin_amdgcn_s_setprio(1);
#pragma unroll
        for (int kh = 0; kh < 2; kh++) {
            sx[kh] = zero16();
            int r = kh * 32 + l31;
#pragma unroll
            for (int s = 0; s < 4; s++) {
                int cs = (2 * s + hi) ^ (r & 7);
                s16x8 kf = *reinterpret_cast<const s16x8*>(&Ks[cur][r * 64 + cs * 8]);
                sx[kh] = __builtin_amdgcn_mfma_f32_32x32x16_bf16(kf, qf[s], sx[kh], 0, 0, 0);
            }
        }
        __builtin_amdgcn_s_setprio(0);

        // mask + in-register max over this lane's 32 keys
        float tmax = -3.0e38f;
#pragma unroll
        for (int kh = 0; kh < 2; kh++)
#pragma unroll
            for (int reg = 0; reg < 16; reg++) {
                float sv = (m32 & (1u << (kh * 16 + reg))) ? -3.0e38f : sx[kh][reg];
                sx[kh][reg] = sv;
                tmax = fmaxf(tmax, sv);
            }
        tmax = fmaxf(tmax, __shfl_xor(tmax, 32));

        // defer-max: rescale only when the row max grows by > 8 (exp2 domain)
        if (__any(tmax > mreg + 8.0f)) {
            float mn = fmaxf(mreg, tmax);
            float sc = exp2_fast(mreg - mn);
            mreg = mn;
            lrow *= sc;
#pragma unroll
            for (int reg = 0; reg < 16; reg++) {
                int qr = (reg & 3) + 8 * (reg >> 2) + 4 * hi;
                float scq = __shfl(sc, qr);
                po[0][reg] *= scq;
                po[1][reg] *= scq;
            }
        }

        // exp2 + row sum (in-register + 1 shfl)
        float psum = 0.f;
#pragma unroll
        for (int kh = 0; kh < 2; kh++)
#pragma unroll
            for (int reg = 0; reg < 16; reg++) {
                float p = exp2_fast(sx[kh][reg] - mreg);
                sx[kh][reg] = p;
                psum += p;
            }
        psum += __shfl_xor(psum, 32);
        lrow += psum;

        // O += P·V : P A-fragment built in registers via cvt_pk + permlane32_swap
        __builtin_amdgcn_s_setprio(1);
#pragma unroll
        for (int ks = 0; ks < 4; ks++) {
            const int kh = ks >> 1, rb = (ks & 1) * 8;
            unsigned o0w0 = cvt_pk_bf16(sx[kh][rb + 0], sx[kh][rb + 1]);
            unsigned o0w1 = cvt_pk_bf16(sx[kh][rb + 2], sx[kh][rb + 3]);
            unsigned o1w0 = cvt_pk_bf16(sx[kh][rb + 4], sx[kh][rb + 5]);
            unsigned o1w1 = cvt_pk_bf16(sx[kh][rb + 6], sx[kh][rb + 7]);
            // swap upper32(a) <-> lower32(b): a' = frag lo-keys, b' = frag hi-keys
            asm("v_permlane32_swap_b32 %0, %1" : "+v"(o0w0), "+v"(o1w0));
            asm("v_permlane32_swap_b32 %0, %1" : "+v"(o0w1), "+v"(o1w1));
            union { unsigned u[4]; s16x8 v; } pk;
            pk.u[0] = o0w0; pk.u[1] = o0w1; pk.u[2] = o1w0; pk.u[3] = o1w1;
#pragma unroll
            for (int dt = 0; dt < 2; dt++) {
                int r  = dt * 32 + l31;
                int cs = (2 * ks + hi) ^ (r & 7);
                s16x8 vf = *reinterpret_cast<const s16x8*>(&Vs[cur][r * 64 + cs * 8]);
                po[dt] = __builtin_amdgcn_mfma_f32_32x32x16_bf16(pk.v, vf, po[dt], 0, 0, 0);
            }
        }
        __builtin_amdgcn_s_setprio(0);

        __syncthreads();   // drains prefetch vmcnt; flips buffer
    }

    // epilogue: po[dt][reg] = O[q = qbase+w*32+qr][d = dt*32+l31]
    float inv = 1.0f / lrow;
#pragma unroll
    for (int reg = 0; reg < 16; reg++) {
        int qr = (reg & 3) + 8 * (reg >> 2) + 4 * hi;
        float invq = __shfl(inv, qr);
        int q = qbase + w * 32 + qr;
#pragma unroll
        for (int dt = 0; dt < 2; dt++) {
            int d = dt * 32 + l31;
            Obuf[((size_t)b * NSEQ + q) * DM + h * DH + d] = f2bf(po[dt][reg] * invq);
        }
    }
}

// ---------------- launch ----------------
extern "C" void kernel_launch(void* const* d_in, const int* in_sizes, int n_in,
                              void* d_out, int out_size, void* d_ws, size_t ws_size,
                              hipStream_t stream) {
    const float* q    = (const float*)d_in[0];
    const void*  mask = (const void*)d_in[1];
    const float* Wq   = (const float*)d_in[2];
    const float* Wk   = (const float*)d_in[3];
    const float* Wv   = (const float*)d_in[4];
    const float* Wo   = (const float*)d_in[5];
    const float* bo   = (const float*)d_in[6];
    float* out = (float*)d_out;

    char* ws = (char*)d_ws;
    const size_t MB = 1024 * 1024;
    unsigned short* qbf  = (unsigned short*)(ws + 0);        // 8 MB (QKV phase)
    unsigned long long* packed = (unsigned long long*)(ws + 0); // 1 MB, reuses qbf AFTER gemm_qkv
    unsigned short* Wqb  = (unsigned short*)(ws + 8  * MB);  // 2 MB
    unsigned short* Wkb  = (unsigned short*)(ws + 10 * MB);  // 2 MB
    unsigned short* Wvb  = (unsigned short*)(ws + 12 * MB);  // 2 MB
    unsigned short* Wob  = (unsigned short*)(ws + 14 * MB);  // 2 MB
    unsigned short* Qh   = (unsigned short*)(ws + 16 * MB);  // 8 MB  [B,H,N,64]
    unsigned short* Kh   = (unsigned short*)(ws + 24 * MB);  // 8 MB  [B,H,N,64]
    unsigned short* VhT  = (unsigned short*)(ws + 32 * MB);  // 8 MB  [B,H,64,N]
    unsigned short* Obuf = (unsigned short*)(ws + 40 * MB);  // 8 MB  [B,N,1024] bf16
    int*            flag = (int*)(ws + 56 * MB);             // 4 B

    hipMemsetAsync(flag, 0, 4, stream);
    mask_detect<<<1024, 256, 0, stream>>>((const unsigned int*)mask, flag);

    cvt_kernel<<<4096, 256, 0, stream>>>(q, qbf, (2 * NSEQ * DM) / 4);
    cvt4_kernel<<<dim3(1024, 4), 256, 0, stream>>>(Wq, Wk, Wv, Wo, Wqb, Wkb, Wvb, Wob);

    gemm_qkv<<<dim3(24, 32), 256, 0, stream>>>(qbf, Wqb, Wkb, Wvb, Qh, Kh, VhT);

    // qbf is dead now; pack the mask into its space (1 MB)
    mask_pack<<<1024, 256, 0, stream>>>(mask, flag, packed);

    attn_kernel<<<512, 256, 0, stream>>>(Qh, Kh, VhT, packed, Obuf);

    gemm_out<<<dim3(8, 64), 256, 0, stream>>>(Obuf, Wob, out, bo);
}